// Round 11
// baseline (892.084 us; speedup 1.0000x reference)
//
#include <hip/hip_runtime.h>
#include <math.h>

#define CDIV(a,b) (((a)+(b)-1)/(b))

__device__ __forceinline__ float siluf(float x){ return x/(1.f+__expf(-x)); }
__device__ __forceinline__ float sigmoidf_(float x){ return 1.f/(1.f+__expf(-x)); }
__device__ __forceinline__ float softplusf(float x){ return x>20.f ? x : log1pf(__expf(x)); }
__device__ __forceinline__ float geluf(float x){ return 0.5f*x*(1.f+erff(x*0.70710678118654752440f)); }

// ---------------- small dense: glob, tt, tms (wave-reduced dots) ----------------
__global__ __launch_bounds__(256) void k_small3(
    const float* __restrict__ gtok, const float* __restrict__ ttok,
    const float* __restrict__ w_glob, const float* __restrict__ b_glob,
    const float* __restrict__ w_ssmt, const float* __restrict__ b_ssmt,
    const float* __restrict__ tm_w, const float* __restrict__ tm_b,
    float* __restrict__ glob, float* __restrict__ tt, float* __restrict__ tms)
{
  int g = blockIdx.x*4 + (threadIdx.x >> 6);
  int lane = threadIdx.x & 63;
  const float* w; const float* src; float bias; float* dst; bool dosilu;
  if (g < 512){
    int b = g >> 6, o = g & 63;
    w = w_glob + (size_t)o*256; src = gtok + (size_t)b*256; bias = b_glob[o]; dst = glob + g; dosilu = false;
  } else if (g < 2560){
    int gg = g - 512; int b = gg >> 8, o = gg & 255;
    w = w_ssmt + (size_t)o*256; src = ttok + (size_t)b*256; bias = b_ssmt[o]; dst = tt + gg; dosilu = true;
  } else {
    int gg = g - 2560; int b = gg >> 7, o = gg & 127;
    w = tm_w + (size_t)o*256; src = ttok + (size_t)b*256; bias = tm_b[o]; dst = tms + gg; dosilu = true;
  }
  float acc = 0.f;
  for (int k = lane; k < 256; k += 64){
    float sv = src[k];
    if (dosilu) sv = siluf(sv);
    acc += sv * w[k];
  }
  acc += __shfl_xor(acc, 1);
  acc += __shfl_xor(acc, 2);
  acc += __shfl_xor(acc, 4);
  acc += __shfl_xor(acc, 8);
  acc += __shfl_xor(acc, 16);
  acc += __shfl_xor(acc, 32);
  if (lane == 0) *dst = acc + bias;
}

// ---------------- transpose w_in [256][64] -> w_inT [64][256] ----------------
__global__ __launch_bounds__(256) void k_wT(const float* __restrict__ w_in, float* __restrict__ w_inT)
{
  int i = blockIdx.x*256 + threadIdx.x;
  if (i >= 16384) return;
  int o = i & 255, k = i >> 8;
  w_inT[k*256 + o] = w_in[o*64 + k];
}

// ---------------- conv weights [64][64][3][3] -> wT[conv][oc][tap*64+ic] ----------------
__global__ __launch_bounds__(256) void k_wconvT(
    const float* __restrict__ w0, const float* __restrict__ w1,
    const float* __restrict__ w2, const float* __restrict__ w3, float* __restrict__ wT4)
{
  int i = blockIdx.x*256 + threadIdx.x;
  if (i >= 4*36864) return;
  int conv = i / 36864; int rem = i % 36864;
  int oc = rem / 576; int k = rem % 576;
  int tap = k >> 6; int ic = k & 63;
  const float* src = conv==0 ? w0 : conv==1 ? w1 : conv==2 ? w2 : w3;
  wT4[i] = src[(size_t)(oc*64+ic)*9 + tap];
}

// ---------------- cond_hf NCHW -> NHWC ----------------
__global__ __launch_bounds__(256) void k_hfT(const float* __restrict__ in, float* __restrict__ out)
{
  int i = blockIdx.x*256 + threadIdx.x;
  if (i >= 524288) return;
  int c = i & 63; int px = i >> 6; int b = px >> 10, hw = px & 1023;
  out[i] = in[((size_t)(b*64+c))*1024 + hw];
}

// ---------------- sf1 prep: Wp=[w_p | beta*w_l], dot1/dot2 from energy branch ----------------
__global__ __launch_bounds__(256) void k_sf1prep(
    const float* __restrict__ sf1_w, const float* __restrict__ en_w, const float* __restrict__ en_b,
    const float* __restrict__ alpha, float* __restrict__ Wp, float* __restrict__ dot12)
{
  float beta = tanhf(alpha[0]);
  int tid = threadIdx.x;
  for (int i = tid; i < 8192; i += 256){
    int o = i >> 7, c = i & 127;
    float v = sf1_w[(size_t)o*192 + c];
    Wp[i] = (c < 64) ? v : beta*v;
  }
  if (tid < 128){
    int o = tid & 63; bool second = tid >= 64;
    float acc = 0.f;
    for (int c2 = 0; c2 < 64; c2++){
      float wv = sf1_w[(size_t)o*192 + 128 + c2];
      acc += wv * (second ? en_b[c2] : en_w[c2]);
    }
    dot12[tid] = acc;
  }
}

// ---------------- LN stage 1: partial sums, 64 blocks per batch ----------------
__global__ __launch_bounds__(256) void k_ln_part(const float* __restrict__ x, double* __restrict__ ps)
{
  int blk = blockIdx.x;                 // 0..511, batch = blk>>6
  int tid = threadIdx.x;
  const float4 v = *(const float4*)(x + (size_t)blk*1024 + tid*4);
  double s  = (double)v.x + (double)v.y + (double)v.z + (double)v.w;
  double ss = (double)v.x*v.x + (double)v.y*v.y + (double)v.z*v.z + (double)v.w*v.w;
  __shared__ double rs[256], rss[256];
  rs[tid] = s; rss[tid] = ss; __syncthreads();
  for (int o = 128; o > 0; o >>= 1){ if (tid < o){ rs[tid]+=rs[tid+o]; rss[tid]+=rss[tid+o]; } __syncthreads(); }
  if (tid == 0){ ps[blk*2] = rs[0]; ps[blk*2+1] = rss[0]; }
}

// ---------------- LN stage 2: fold 64 partials per batch -> mean/rstd ----------------
__global__ __launch_bounds__(64) void k_ln_fin(const double* __restrict__ ps, float* __restrict__ st, float eps)
{
  int b = blockIdx.x; int t = threadIdx.x;
  double s  = ps[(b*64+t)*2];
  double ss = ps[(b*64+t)*2+1];
  for (int o = 32; o > 0; o >>= 1){
    s  += __shfl_xor(s,  o);
    ss += __shfl_xor(ss, o);
  }
  if (t == 0){
    double m = s/65536.0, var = ss/65536.0 - m*m;
    st[b*2] = (float)m; st[b*2+1] = (float)(1.0/sqrt(var + (double)eps));
  }
}

// ---------------- x_norm -> xp = @ w_in.T ; NHWC outputs ----------------
__global__ __launch_bounds__(256) void k_xp(
    const float* __restrict__ x, const float* __restrict__ cond,
    const float* __restrict__ ln, const float* __restrict__ glob,
    const float* __restrict__ w_inT, const float* __restrict__ b_in,
    const float* __restrict__ gamma_gate,
    float* __restrict__ xss, float* __restrict__ xgate, float* __restrict__ cbn)
{
  int p0 = blockIdx.x * 16;
  int tid = threadIdx.x;
  __shared__ float xv[64*16];   // [c][p]
  __shared__ float cf[64*16];   // [c][p] cond_feat+glob
  for (int i = tid; i < 1024; i += 256){
    int c = i >> 4, p = i & 15;
    int pix = p0 + p; int b = pix >> 10, hw = pix & 1023;
    float mean = ln[b*2], rstd = ln[b*2+1];
    float v  = x[((size_t)(b*64+c))*1024 + hw];
    float sc = cond[((size_t)(b*512+64+c))*1024 + hw];
    float sh = cond[((size_t)(b*512+c))*1024 + hw];
    xv[c*16+p] = ((v-mean)*rstd)*(1.f+sc)+sh;
    cf[c*16+p] = cond[((size_t)(b*512+384+c))*1024 + hw] + glob[b*64+c];
  }
  __syncthreads();
  int o = tid;
  float acc[16];
  float bi = b_in[o];
  #pragma unroll
  for (int p = 0; p < 16; p++) acc[p] = bi;
  for (int k = 0; k < 64; k++){
    float wv = w_inT[k*256 + o];
    #pragma unroll
    for (int p = 0; p < 16; p++) acc[p] = fmaf(xv[k*16+p], wv, acc[p]);
  }
  float gg = gamma_gate[0];
  #pragma unroll
  for (int p = 0; p < 16; p++){
    int pix = p0 + p;
    if (o < 128){
      xss[(size_t)pix*128 + o] = acc[p];
    } else {
      int c = o - 128;
      float cb = cf[(c&63)*16+p];
      float g = acc[p] + gg*cb;
      xgate[(size_t)pix*128 + c] = siluf(g);
      if (c < 64) cbn[(size_t)pix*64 + c] = cb;
    }
  }
}

// ---------------- depthwise 3x3 conv + silu + ssm modulation + 4-dir scatter (NHWC) ----------------
__global__ __launch_bounds__(256) void k_dwconv(
    const float* __restrict__ xss, const float* __restrict__ w_dw, const float* __restrict__ b_dw,
    const float* __restrict__ cbn, const float* __restrict__ tt, const float* __restrict__ gamma_main,
    float* __restrict__ seq_x)
{
  int i = blockIdx.x*256 + threadIdx.x;
  if (i >= 8*1024*128) return;
  int c = i & 127; int pix = i >> 7;
  int b = pix >> 10, hw = pix & 1023;
  int h = hw >> 5, w = hw & 31;
  float acc = b_dw[c];
  const float* wp = w_dw + c*9;
  const float* src = xss + ((size_t)b*1024)*128;
  #pragma unroll
  for (int ky = 0; ky < 3; ky++){
    int y = h + ky - 1; if (y < 0 || y > 31) continue;
    #pragma unroll
    for (int kx = 0; kx < 3; kx++){
      int xw = w + kx - 1; if (xw < 0 || xw > 31) continue;
      acc += src[(size_t)(y*32+xw)*128 + c]*wp[ky*3+kx];
    }
  }
  float v = siluf(acc);
  float cb = cbn[(size_t)pix*64 + (c&63)];
  v = (v + gamma_main[0]*cb)*(1.f+tt[b*256+c]) + tt[b*256+128+c];
  int l3 = w*32 + h;
  seq_x[(((size_t)b*1024)      + hw       )*128 + c] = v;
  seq_x[(((size_t)(8+b)*1024)  + (1023-hw))*128 + c] = v;
  seq_x[(((size_t)(16+b)*1024) + l3       )*128 + c] = v;
  seq_x[(((size_t)(24+b)*1024) + (1023-l3))*128 + c] = v;
}

// ---------------- generic fp32 GEMM: C[M,N] = act(A[M,K] @ W[N,K]^T + bias) ----------------
template<int ACT>  // 0 none, 1 silu
__global__ __launch_bounds__(256) void gemm_nt(
    const float* __restrict__ A, const float* __restrict__ W, const float* __restrict__ bias,
    float* __restrict__ C, int M, int N, int K)
{
  __shared__ float As[16][68];
  __shared__ float Ws[16][68];
  int bm = blockIdx.y*64, bn = blockIdx.x*64;
  int tid = threadIdx.x;
  int tm = (tid >> 4) << 2;
  int tn = (tid & 15) << 2;
  float acc[4][4] = {};
  for (int k0 = 0; k0 < K; k0 += 16){
    #pragma unroll
    for (int i = 0; i < 4; i++){
      int idx = tid + 256*i;
      int r = idx >> 4, cc = idx & 15;
      int gm = bm + r;
      As[cc][r] = (gm < M) ? A[(size_t)gm*K + k0 + cc] : 0.f;
      int gn = bn + r;
      Ws[cc][r] = (gn < N) ? W[(size_t)gn*K + k0 + cc] : 0.f;
    }
    __syncthreads();
    #pragma unroll
    for (int kk = 0; kk < 16; kk++){
      float a[4], w[4];
      #pragma unroll
      for (int i = 0; i < 4; i++) a[i] = As[kk][tm+i];
      #pragma unroll
      for (int j = 0; j < 4; j++) w[j] = Ws[kk][tn+j];
      #pragma unroll
      for (int i = 0; i < 4; i++)
        #pragma unroll
        for (int j = 0; j < 4; j++) acc[i][j] = fmaf(a[i], w[j], acc[i][j]);
    }
    __syncthreads();
  }
  #pragma unroll
  for (int i = 0; i < 4; i++){
    int gm = bm + tm + i; if (gm >= M) continue;
    #pragma unroll
    for (int j = 0; j < 4; j++){
      int gn = bn + tn + j; if (gn >= N) continue;
      float v = acc[i][j] + (bias ? bias[gn] : 0.f);
      if (ACT == 1) v = siluf(v);
      C[(size_t)gm*N + gn] = v;
    }
  }
}

// ---------------- fused in_proj GEMM: both halves, A read once ----------------
__global__ __launch_bounds__(256) void gemm_in(
    const float* __restrict__ A, const float* __restrict__ W,
    float* __restrict__ Cx, float* __restrict__ Cz)
{
  __shared__ float As[16][68];
  __shared__ float Ws[16][68];
  int bm = blockIdx.y*64, bn = blockIdx.x*64;   // N total 512
  int tid = threadIdx.x;
  int tm = (tid >> 4) << 2;
  int tn = (tid & 15) << 2;
  float acc[4][4] = {};
  for (int k0 = 0; k0 < 128; k0 += 16){
    #pragma unroll
    for (int i = 0; i < 4; i++){
      int idx = tid + 256*i;
      int r = idx >> 4, cc = idx & 15;
      As[cc][r] = A[(size_t)(bm+r)*128 + k0 + cc];
      Ws[cc][r] = W[(size_t)(bn+r)*128 + k0 + cc];
    }
    __syncthreads();
    #pragma unroll
    for (int kk = 0; kk < 16; kk++){
      float a[4], w[4];
      #pragma unroll
      for (int i = 0; i < 4; i++) a[i] = As[kk][tm+i];
      #pragma unroll
      for (int j = 0; j < 4; j++) w[j] = Ws[kk][tn+j];
      #pragma unroll
      for (int i = 0; i < 4; i++)
        #pragma unroll
        for (int j = 0; j < 4; j++) acc[i][j] = fmaf(a[i], w[j], acc[i][j]);
    }
    __syncthreads();
  }
  #pragma unroll
  for (int i = 0; i < 4; i++){
    int gm = bm + tm + i;
    #pragma unroll
    for (int j = 0; j < 4; j++){
      int gn = bn + tn + j;
      float v = acc[i][j];
      if (gn < 256) Cx[(size_t)gm*256 + gn] = v;
      else          Cz[(size_t)gm*256 + gn - 256] = siluf(v);
    }
  }
}

// ---------------- implicit-GEMM 3x3 conv (NHWC, K split by ky) ----------------
// A: [8192][64] NHWC. wT: [64][576] (tap-major k). part: [3][8192][64].
__global__ __launch_bounds__(256) void k_conv_gemm(
    const float* __restrict__ A, const float* __restrict__ wT, float* __restrict__ part)
{
  __shared__ float As[16][68];
  __shared__ float Ws[16][68];
  int kc = blockIdx.x;                // ky chunk 0..2
  int bm = blockIdx.y*64;
  int tid = threadIdx.x;
  int tm = (tid >> 4) << 2;
  int tn = (tid & 15) << 2;
  int dy = kc - 1;
  float acc[4][4] = {};
  for (int k0 = 0; k0 < 192; k0 += 16){
    int j  = k0 >> 6;                 // kx index (16 | 64 so single tap per k0 block)
    int ic0 = k0 & 63;
    int dx = j - 1;
    #pragma unroll
    for (int i = 0; i < 4; i++){
      int idx = tid + 256*i;
      int r = idx >> 4, kk = idx & 15;
      int gm = bm + r;
      int hw = gm & 1023;
      int h = hw >> 5, w = hw & 31;
      int hh = h + dy, ww = w + dx;
      bool ok = (hh >= 0) && (hh < 32) && (ww >= 0) && (ww < 32);
      As[kk][r] = ok ? A[(size_t)(gm + dy*32 + dx)*64 + ic0 + kk] : 0.f;
      Ws[kk][r] = wT[(size_t)r*576 + kc*192 + k0 + kk];
    }
    __syncthreads();
    #pragma unroll
    for (int kk = 0; kk < 16; kk++){
      float a[4], w4[4];
      #pragma unroll
      for (int i = 0; i < 4; i++) a[i] = As[kk][tm+i];
      #pragma unroll
      for (int jj = 0; jj < 4; jj++) w4[jj] = Ws[kk][tn+jj];
      #pragma unroll
      for (int i = 0; i < 4; i++)
        #pragma unroll
        for (int jj = 0; jj < 4; jj++) acc[i][jj] = fmaf(a[i], w4[jj], acc[i][jj]);
    }
    __syncthreads();
  }
  float* dst = part + ((size_t)kc*8192 + bm)*64;
  #pragma unroll
  for (int i = 0; i < 4; i++)
    #pragma unroll
    for (int jj = 0; jj < 4; jj++)
      dst[(size_t)(tm+i)*64 + tn+jj] = acc[i][jj];
}

// ---------------- conv partial reduce + bias + resid ----------------
__global__ __launch_bounds__(256) void k_conv_red(
    const float* __restrict__ part, const float* __restrict__ bias,
    const float* __restrict__ resid, int residLd,
    float* __restrict__ out, int outLd)
{
  int i = blockIdx.x*256 + threadIdx.x;
  if (i >= 524288) return;
  int oc = i & 63; int px = i >> 6;
  float v = part[i] + part[524288 + i] + part[1048576 + i];
  if (bias) v += bias[oc];
  if (resid) v += resid[(size_t)px*residLd + oc];
  out[(size_t)px*outLd + oc] = v;
}

// ---------------- sfuse GEMM: C = cat[8192][128] @ Wp[64][128]^T + e*dot1 + dot2 ----------------
__global__ __launch_bounds__(256) void gemm_sfuse(
    const float* __restrict__ A, const float* __restrict__ Wp,
    const float* __restrict__ eB, const float* __restrict__ dot12,
    float* __restrict__ C)
{
  __shared__ float As[16][68];
  __shared__ float Ws[16][68];
  int bm = blockIdx.x*64;
  int tid = threadIdx.x;
  int tm = (tid >> 4) << 2;
  int tn = (tid & 15) << 2;
  float acc[4][4] = {};
  for (int k0 = 0; k0 < 128; k0 += 16){
    #pragma unroll
    for (int i = 0; i < 4; i++){
      int idx = tid + 256*i;
      int r = idx >> 4, cc = idx & 15;
      As[cc][r] = A[(size_t)(bm+r)*128 + k0 + cc];
      Ws[cc][r] = Wp[(size_t)r*128 + k0 + cc];
    }
    __syncthreads();
    #pragma unroll
    for (int kk = 0; kk < 16; kk++){
      float a[4], w[4];
      #pragma unroll
      for (int i = 0; i < 4; i++) a[i] = As[kk][tm+i];
      #pragma unroll
      for (int j = 0; j < 4; j++) w[j] = Ws[kk][tn+j];
      #pragma unroll
      for (int i = 0; i < 4; i++)
        #pragma unroll
        for (int j = 0; j < 4; j++) acc[i][j] = fmaf(a[i], w[j], acc[i][j]);
    }
    __syncthreads();
  }
  #pragma unroll
  for (int i = 0; i < 4; i++){
    int gm = bm + tm + i;
    float e = eB[gm];
    #pragma unroll
    for (int j = 0; j < 4; j++){
      int gn = tn + j;
      C[(size_t)gm*64 + gn] = acc[i][j] + e*dot12[gn] + dot12[64+gn];
    }
  }
}

// ---------------- causal depthwise conv1d (k=4) + silu ----------------
__global__ __launch_bounds__(256) void k_conv1d(
    const float* __restrict__ xin, const float* __restrict__ w, const float* __restrict__ bias,
    float* __restrict__ out)
{
  int i = blockIdx.x*256 + threadIdx.x;
  if (i >= 32*1024*256) return;
  int d = i & 255; int l = (i >> 8) & 1023; int b = i >> 18;
  const float* base = xin + ((size_t)b*1024)*256 + d;
  float acc = bias[d];
  const float* wp = w + d*4;
  #pragma unroll
  for (int k = 0; k < 4; k++){
    int ll = l - 3 + k;
    if (ll >= 0) acc += base[(size_t)ll*256]*wp[k];
  }
  out[i] = siluf(acc);
}

// ---------------- chunked scan, phase A (dt fused inline), 32 chunks x 32 steps ----------------
__global__ __launch_bounds__(256) void k_scanA(
    const float* __restrict__ xm, const float* __restrict__ xdbl,
    const float* __restrict__ dtw, const float* __restrict__ dtb,
    const float* __restrict__ Alog, float* __restrict__ Pb, float* __restrict__ Qb)
{
  int bb = blockIdx.x >> 5, ch = blockIdx.x & 31;
  int d = threadIdx.x;
  float an[16];
  {
    const float4* a4 = (const float4*)(Alog + d*16);
    #pragma unroll
    for (int j = 0; j < 4; j++){
      float4 t = a4[j];
      an[4*j+0] = -__expf(t.x); an[4*j+1] = -__expf(t.y); an[4*j+2] = -__expf(t.z); an[4*j+3] = -__expf(t.w);
    }
  }
  float w8[8];
  {
    const float4* w4 = (const float4*)(dtw + d*8);
    float4 a = w4[0], b2 = w4[1];
    w8[0]=a.x; w8[1]=a.y; w8[2]=a.z; w8[3]=a.w; w8[4]=b2.x; w8[5]=b2.y; w8[6]=b2.z; w8[7]=b2.w;
  }
  float dtb_d = dtb[d];
  float P[16], Q[16];
  #pragma unroll
  for (int n = 0; n < 16; n++){ P[n] = 1.f; Q[n] = 0.f; }
  int m0 = bb*1024 + ch*32;
  for (int s = 0; s < 32; s++){
    int m = m0 + s;
    const float4* X4 = (const float4*)(xdbl + (size_t)m*40);
    float4 x0 = X4[0], x1 = X4[1];
    float t = dtb_d;
    t = fmaf(x0.x,w8[0],t); t = fmaf(x0.y,w8[1],t); t = fmaf(x0.z,w8[2],t); t = fmaf(x0.w,w8[3],t);
    t = fmaf(x1.x,w8[4],t); t = fmaf(x1.y,w8[5],t); t = fmaf(x1.z,w8[6],t); t = fmaf(x1.w,w8[7],t);
    float dtv = softplusf(t);
    float xv  = xm[(size_t)m*256 + d];
    const float4* B4 = (const float4*)(xdbl + (size_t)m*40 + 8);
    float Bv[16];
    #pragma unroll
    for (int j = 0; j < 4; j++){ float4 tt2 = B4[j]; Bv[4*j]=tt2.x; Bv[4*j+1]=tt2.y; Bv[4*j+2]=tt2.z; Bv[4*j+3]=tt2.w; }
    float dx = dtv*xv;
    #pragma unroll
    for (int n = 0; n < 16; n++){
      float a = __expf(dtv*an[n]);
      Q[n] = fmaf(a, Q[n], dx*Bv[n]);
      P[n] *= a;
    }
  }
  size_t base = ((size_t)(blockIdx.x*256 + d))*16;
  float4* p4 = (float4*)(Pb + base);
  float4* q4 = (float4*)(Qb + base);
  #pragma unroll
  for (int j = 0; j < 4; j++){
    p4[j] = make_float4(P[4*j], P[4*j+1], P[4*j+2], P[4*j+3]);
    q4[j] = make_float4(Q[4*j], Q[4*j+1], Q[4*j+2], Q[4*j+3]);
  }
}

// ---------------- chunked scan, phase C: fold prefix, rescan (dt inline), fused ymod ----------------
__global__ __launch_bounds__(256) void k_scanC(
    const float* __restrict__ xm, const float* __restrict__ xdbl,
    const float* __restrict__ dtw, const float* __restrict__ dtb,
    const float* __restrict__ Alog, const float* __restrict__ Pb, const float* __restrict__ Qb,
    const float* __restrict__ Dw, const float* __restrict__ zsilu, float* __restrict__ yout)
{
  int bb = blockIdx.x >> 5, ch = blockIdx.x & 31;
  int d = threadIdx.x;
  float an[16];
  {
    const float4* a4 = (const float4*)(Alog + d*16);
    #pragma unroll
    for (int j = 0; j < 4; j++){
      float4 t = a4[j];
      an[4*j+0] = -__expf(t.x); an[4*j+1] = -__expf(t.y); an[4*j+2] = -__expf(t.z); an[4*j+3] = -__expf(t.w);
    }
  }
  float w8[8];
  {
    const float4* w4 = (const float4*)(dtw + d*8);
    float4 a = w4[0], b2 = w4[1];
    w8[0]=a.x; w8[1]=a.y; w8[2]=a.z; w8[3]=a.w; w8[4]=b2.x; w8[5]=b2.y; w8[6]=b2.z; w8[7]=b2.w;
  }
  float dtb_d = dtb[d];
  float h[16];
  #pragma unroll
  for (int n = 0; n < 16; n++) h[n] = 0.f;
  for (int c2 = 0; c2 < ch; c2++){
    size_t base = ((size_t)((bb*32+c2)*256 + d))*16;
    const float4* p4 = (const float4*)(Pb + base);
    const float4* q4 = (const float4*)(Qb + base);
    #pragma unroll
    for (int j = 0; j < 4; j++){
      float4 p = p4[j]; float4 q = q4[j];
      h[4*j+0] = fmaf(p.x, h[4*j+0], q.x);
      h[4*j+1] = fmaf(p.y, h[4*j+1], q.y);
      h[4*j+2] = fmaf(p.z, h[4*j+2], q.z);
      h[4*j+3] = fmaf(p.w, h[4*j+3], q.w);
    }
  }
  float Dd = Dw[d];
  int m0 = bb*1024 + ch*32;
  for (int s = 0; s < 32; s++){
    int m = m0 + s;
    const float4* X4 = (const float4*)(xdbl + (size_t)m*40);
    float4 x0 = X4[0], x1 = X4[1];
    float t = dtb_d;
    t = fmaf(x0.x,w8[0],t); t = fmaf(x0.y,w8[1],t); t = fmaf(x0.z,w8[2],t); t = fmaf(x0.w,w8[3],t);
    t = fmaf(x1.x,w8[4],t); t = fmaf(x1.y,w8[5],t); t = fmaf(x1.z,w8[6],t); t = fmaf(x1.w,w8[7],t);
    float dtv = softplusf(t);
    float xv  = xm[(size_t)m*256 + d];
    const float4* B4 = (const float4*)(xdbl + (size_t)m*40 + 8);
    const float4* C4 = (const float4*)(xdbl + (size_t)m*40 + 24);
    float Bv[16], Cv[16];
    #pragma unroll
    for (int j = 0; j < 4; j++){
      float4 tt2 = B4[j]; Bv[4*j]=tt2.x; Bv[4*j+1]=tt2.y; Bv[4*j+2]=tt2.z; Bv[4*j+3]=tt2.w;
      float4 u = C4[j]; Cv[4*j]=u.x; Cv[4*j+1]=u.y; Cv[4*j+2]=u.z; Cv[4*j+3]=u.w;
    }
    float dx = dtv*xv;
    float y = 0.f;
    #pragma unroll
    for (int n = 0; n < 16; n++){
      float a = __expf(dtv*an[n]);
      h[n] = fmaf(a, h[n], dx*Bv[n]);
      y = fmaf(h[n], Cv[n], y);
    }
    float z = zsilu[(size_t)m*256 + d];
    yout[(size_t)m*256 + d] = (y + xv*Dd)*z;
  }
}

// ---------------- gather 4 directions + gate (NHWC) ----------------
__global__ __launch_bounds__(256) void k_fuse(
    const float* __restrict__ mo, const float* __restrict__ xgate, float* __restrict__ xf)
{
  int i = blockIdx.x*256 + threadIdx.x;
  if (i >= 8*1024*128) return;
  int c = i & 127; int pix = i >> 7;
  int b = pix >> 10, hw = pix & 1023;
  int h = hw >> 5, w = hw & 31; int l3 = w*32 + h;
  float o1 = mo[(((size_t)b*1024)      + hw       )*128 + c];
  float o2 = mo[(((size_t)(8+b)*1024)  + (1023-hw))*128 + c];
  float o3 = mo[(((size_t)(16+b)*1024) + l3       )*128 + c];
  float o4 = mo[(((size_t)(24+b)*1024) + (1023-l3))*128 + c];
  xf[(size_t)pix*128 + c] = (o1+o2+o3+o4)*xgate[(size_t)pix*128 + c];
}

// ---------------- physics: blurs, diffs, std normalize, energy ----------------
__global__ __launch_bounds__(256) void k_phys1(
    const float* __restrict__ pan, float* __restrict__ dS, float* __restrict__ dL, float* __restrict__ eB)
{
  int b = blockIdx.x; int tid = threadIdx.x;
  __shared__ float tile[1024];
  __shared__ float ks[9];
  __shared__ float kl[25];
  __shared__ float red[256];
  __shared__ float sh_sig[2];
  __shared__ float sh_emax;
  for (int i = tid; i < 1024; i += 256) tile[i] = pan[b*1024+i];
  if (tid == 0){
    float s = 0;
    for (int j = 0; j < 3; j++) for (int i2 = 0; i2 < 3; i2++){
      float dy = (float)(j-1), dx = (float)(i2-1);
      float g = expf(-(dx*dx+dy*dy)*0.5f); ks[j*3+i2] = g; s += g;
    }
    for (int i2 = 0; i2 < 9; i2++) ks[i2] /= s;
    s = 0;
    for (int j = 0; j < 5; j++) for (int i2 = 0; i2 < 5; i2++){
      float dy = (float)(j-2), dx = (float)(i2-2);
      float g = expf(-(dx*dx+dy*dy)*0.125f); kl[j*5+i2] = g; s += g;
    }
    for (int i2 = 0; i2 < 25; i2++) kl[i2] /= s;
  }
  __syncthreads();
  float ds4[4], dl4[4], e4[4];
  float s_s = 0, ss_s = 0, s_l = 0, ss_l = 0;
  for (int j = 0; j < 4; j++){
    int px = tid + 256*j; int h = px >> 5, w = px & 31;
    float bs = 0;
    for (int ky = 0; ky < 3; ky++){
      int y = h + ky - 1; y = y < 0 ? -y : (y > 31 ? 62-y : y);
      for (int kx = 0; kx < 3; kx++){
        int xx = w + kx - 1; xx = xx < 0 ? -xx : (xx > 31 ? 62-xx : xx);
        bs += tile[y*32+xx]*ks[ky*3+kx];
      }
    }
    float bl = 0;
    for (int ky = 0; ky < 5; ky++){
      int y = h + ky - 2; y = y < 0 ? -y : (y > 31 ? 62-y : y);
      for (int kx = 0; kx < 5; kx++){
        int xx = w + kx - 2; xx = xx < 0 ? -xx : (xx > 31 ? 62-xx : xx);
        bl += tile[y*32+xx]*kl[ky*5+kx];
      }
    }
    float v = tile[px];
    float a = v - bs, c = v - bl;
    ds4[j] = a; dl4[j] = c;
    s_s += a; ss_s += a*a; s_l += c; ss_l += c*c;
  }
  #define BLK_RED(val, outvar) red[tid]=(val); __syncthreads(); \
    for (int o_=128;o_>0;o_>>=1){ if (tid<o_) red[tid]+=red[tid+o_]; __syncthreads(); } \
    float outvar = red[0]; __syncthreads();
  BLK_RED(s_s,  tot_s)
  BLK_RED(ss_s, tot_ss)
  BLK_RED(s_l,  tot_l)
  BLK_RED(ss_l, tot_ll)
  if (tid == 0){
    float var_s = (tot_ss - tot_s*tot_s/1024.f)/1023.f;
    float var_l = (tot_ll - tot_l*tot_l/1024.f)/1023.f;
    sh_sig[0] = sqrtf(var_s) + 1e-6f;
    sh_sig[1] = sqrtf(var_l) + 1e-6f;
  }
  __syncthreads();
  float inv_s = 1.f/sh_sig[0], inv_l = 1.f/sh_sig[1];
  float emax = 0;
  for (int j = 0; j < 4; j++){
    ds4[j] *= inv_s; dl4[j] *= inv_l;
    e4[j] = fabsf(ds4[j]) + fabsf(dl4[j]);
    emax = fmaxf(emax, e4[j]);
  }
  red[tid] = emax; __syncthreads();
  for (int o_ = 128; o_ > 0; o_ >>= 1){ if (tid < o_) red[tid] = fmaxf(red[tid], red[tid+o_]); __syncthreads(); }
  if (tid == 0) sh_emax = red[0];
  __syncthreads();
  float einv = 1.f/(sh_emax + 1e-6f);
  for (int j = 0; j < 4; j++){
    int px = tid + 256*j;
    dS[b*1024+px] = ds4[j];
    dL[b*1024+px] = dl4[j];
    eB[b*1024+px] = e4[j]*einv;
  }
}

// ---------------- pp1: conv 2->64, pad=1 (zeros), NHWC out ----------------
__global__ __launch_bounds__(256) void k_conv_pp1_n(
    const float* __restrict__ dS, const float* __restrict__ dL,
    const float* __restrict__ w, const float* __restrict__ bias, float* __restrict__ out)
{
  int i = blockIdx.x*256 + threadIdx.x;
  if (i >= 524288) return;
  int o = i & 63; int px = i >> 6;
  int b = px >> 10, hw = px & 1023;
  int h = hw >> 5, ww = hw & 31;
  float acc = bias[o];
  for (int ic = 0; ic < 2; ic++){
    const float* src = (ic ? dL : dS) + b*1024;
    const float* wp = w + (o*2+ic)*9;
    #pragma unroll
    for (int ky = 0; ky < 3; ky++){
      int y = h + ky - 1; if (y < 0 || y > 31) continue;
      #pragma unroll
      for (int kx = 0; kx < 3; kx++){
        int xx = ww + kx - 1; if (xx < 0 || xx > 31) continue;
        acc += src[y*32+xx]*wp[ky*3+kx];
      }
    }
  }
  out[i] = acc;
}

// ---------------- group-norm stats (NHWC, ld=64): block per (b,g) ----------------
__global__ __launch_bounds__(256) void k_gn_stats_n(const float* __restrict__ x, float* __restrict__ st, float eps)
{
  int blk = blockIdx.x; int tid = threadIdx.x;
  int b = blk >> 5, g = blk & 31;
  const float* p = x + (size_t)b*1024*64 + g*2;
  double s = 0.0, ss = 0.0;
  for (int px = tid; px < 1024; px += 256){
    float2 v = *(const float2*)(p + (size_t)px*64);
    s += v.x + v.y; ss += (double)v.x*v.x + (double)v.y*v.y;
  }
  __shared__ double rs[256], rss[256];
  rs[tid] = s; rss[tid] = ss; __syncthreads();
  for (int o = 128; o > 0; o >>= 1){ if (tid < o){ rs[tid]+=rs[tid+o]; rss[tid]+=rss[tid+o]; } __syncthreads(); }
  if (tid == 0){
    double m = rs[0]/2048.0, var = rss[0]/2048.0 - m*m;
    st[blk*2] = (float)m; st[blk*2+1] = (float)(1.0/sqrt(var + (double)eps));
  }
}

// ---------------- apply GN (affine) + silu (NHWC) ----------------
__global__ __launch_bounds__(256) void k_gn_apply_n(
    const float* __restrict__ x, const float* __restrict__ st,
    const float* __restrict__ gamma, const float* __restrict__ beta, float* __restrict__ out)
{
  int i = blockIdx.x*256 + threadIdx.x;
  if (i >= 524288) return;
  int c = i & 63; int px = i >> 6; int b = px >> 10;
  int g = c >> 1;
  float m = st[(b*32+g)*2], r = st[(b*32+g)*2+1];
  float v = (x[i]-m)*r*gamma[c]+beta[c];
  out[i] = siluf(v);
}

// ---------------- a = silu(gn_noaffine(dseed)*(1+t_scale)+t_shift) (NHWC in/out) ----------------
__global__ __launch_bounds__(256) void k_apply_a_n(
    const float* __restrict__ x, const float* __restrict__ st, const float* __restrict__ tms,
    float* __restrict__ out)
{
  int i = blockIdx.x*256 + threadIdx.x;
  if (i >= 524288) return;
  int c = i & 63; int px = i >> 6; int b = px >> 10;
  int g = c >> 1;
  float m = st[(b*32+g)*2], r = st[(b*32+g)*2+1];
  float v = (x[i]-m)*r;
  v = v*(1.f+tms[b*128+c]) + tms[b*128+64+c];
  out[i] = siluf(v);
}

// ---------------- xmod (NHWC) = xf*(1+scale)+shift ----------------
__global__ __launch_bounds__(256) void k_xmod(
    const float* __restrict__ xf, const float* __restrict__ ph, float* __restrict__ xmod)
{
  int i = blockIdx.x*256 + threadIdx.x;
  if (i >= 8*1024*128) return;
  int c = i & 127; int pix = i >> 7;
  const float* pp = ph + (size_t)pix*384;
  float conf = pp[256 + c];
  float g = 0.3f + 0.7f*sigmoidf_(conf);
  float sc  = pp[c]*g;
  float shf = pp[128 + c]*g;
  xmod[(size_t)pix*128 + c] = xf[(size_t)pix*128 + c]*(1.f+sc)+shf;
}

// ---------------- out-proj epilogue: xx = x + xo*sm_gate (NCHW) ----------------
__global__ __launch_bounds__(256) void k_opj_epi(
    const float* __restrict__ xo, const float* __restrict__ x, const float* __restrict__ cond,
    float* __restrict__ xx)
{
  int i = blockIdx.x*256 + threadIdx.x;
  if (i >= 8*64*1024) return;
  int hw = i & 1023; int c = (i >> 10) & 63; int b = i >> 16;
  int pix = b*1024 + hw;
  float g = cond[((size_t)(b*512+128+c))*1024 + hw];
  xx[i] = x[i] + xo[(size_t)pix*64 + c]*g;
}

// ---------------- fc1 with fused LN2-modulated A-load; gelu epilogue ----------------
__global__ __launch_bounds__(256) void gemm_fc1(
    const float* __restrict__ xx, const float* __restrict__ cond, const float* __restrict__ ln2,
    const float* __restrict__ W, const float* __restrict__ bias, float* __restrict__ C)
{
  __shared__ float As[16][68];
  __shared__ float Ws[16][68];
  const int N = 256, K = 64;
  int bm = blockIdx.y*64, bn = blockIdx.x*64;
  int tid = threadIdx.x;
  int tm = (tid >> 4) << 2;
  int tn = (tid & 15) << 2;
  float acc[4][4] = {};
  for (int k0 = 0; k0 < K; k0 += 16){
    #pragma unroll
    for (int i = 0; i < 4; i++){
      int idx = tid + 256*i;
      int r = idx & 63, cc = idx >> 6;
      int gm = bm + r;
      int b = gm >> 10, hw = gm & 1023;
      int k = k0 + cc;
      float mean = ln2[b*2], rstd = ln2[b*2+1];
      float v  = (xx[((size_t)(b*64+k))*1024 + hw] - mean)*rstd;
      float sc = cond[((size_t)(b*512+256+k))*1024 + hw];
      float sh = cond[((size_t)(b*512+192+k))*1024 + hw];
      As[cc][r] = v*(1.f+sc)+sh;
      int r2 = idx >> 4, cc2 = idx & 15;
      int gn = bn + r2;
      Ws[cc2][r2] = W[(size_t)gn*K + k0 + cc2];
    }
    __syncthreads();
    #pragma unroll
    for (int kk = 0; kk < 16; kk++){
      float a[4], w[4];
      #pragma unroll
      for (int i = 0; i < 4; i++) a[i] = As[kk][tm+i];
      #pragma unroll
      for (int j = 0; j < 4; j++) w[j] = Ws[kk][tn+j];
      #pragma unroll
      for (int i = 0; i < 4; i++)
        #pragma unroll
        for (int j = 0; j < 4; j++) acc[i][j] = fmaf(a[i], w[j], acc[i][j]);
    }
    __syncthreads();
  }
  #pragma unroll
  for (int i = 0; i < 4; i++){
    int gm = bm + tm + i;
    #pragma unroll
    for (int j = 0; j < 4; j++){
      int gn = bn + tn + j;
      C[(size_t)gm*N + gn] = geluf(acc[i][j] + bias[gn]);
    }
  }
}

// ---------------- MLP epilogue: out = xx + mo*sp_gate (NCHW) ----------------
__global__ __launch_bounds__(256) void k_mlp_epi(
    const float* __restrict__ mo, const float* __restrict__ xx, const float* __restrict__ cond,
    float* __restrict__ out)
{
  int i = blockIdx.x*256 + threadIdx.x;
  if (i >= 8*64*1024) return;
  int hw = i & 1023; int c = (i >> 10) & 63; int b = i >> 16;
  int pix = b*1024 + hw;
  float g = cond[((size_t)(b*512+320+c))*1024 + hw];
  out[i] = xx[i] + mo[(size_t)pix*64 + c]*g;
}

// =====================================================================
extern "C" void kernel_launch(void* const* d_in, const int* in_sizes, int n_in,
                              void* d_out, int out_size, void* d_ws, size_t ws_size,
                              hipStream_t stream)
{
  const float* x         = (const float*)d_in[0];
  const float* cond_base = (const float*)d_in[1];
  const float* cond_hf   = (const float*)d_in[2];
  const float* pan_raw   = (const float*)d_in[3];
  const float* gtok      = (const float*)d_in[4];
  const float* ttok      = (const float*)d_in[5];
  const float* w_in      = (const float*)d_in[6];
  const float* b_in      = (const float*)d_in[7];
  const float* w_dw      = (const float*)d_in[8];
  const float* b_dw      = (const float*)d_in[9];
  const float* w_glob    = (const float*)d_in[10];
  const float* b_glob    = (const float*)d_in[11];
  const float* w_ssmt    = (const float*)d_in[12];
  const float* b_ssmt    = (const float*)d_in[13];
  const float* gamma_gate= (const float*)d_in[14];
  const float* gamma_main= (const float*)d_in[15];
  const float* w_out     = (const float*)d_in[16];
  const float* b_out     = (const float*)d_in[17];
  const float* w_fc1     = (const float*)d_in[18];
  const float* b_fc1     = (const float*)d_in[19];
  const float* w_fc2     = (const float*)d_in[20];
  const float* b_fc2     = (const float*)d_in[21];
  const float* m_in_w    = (const float*)d_in[22];
  const float* m_conv_w  = (const float*)d_in[23];
  const float* m_conv_b  = (const float*)d_in[24];
  const float* m_xproj_w = (const float*)d_in[25];
  const float* m_dt_w    = (const float*)d_in[26];
  const float* m_dt_b    = (const float*)d_in[27];
  const float* m_Alog    = (const float*)d_in[28];
  const float* m_D       = (const float*)d_in[29];
  const float* m_out_w   = (const float*)d_in[30];
  const float* pp1_w     = (const float*)d_in[31];
  const float* pp1_b     = (const float*)d_in[32];
  const float* pp_g1     = (const float*)d_in[33];
  const float* pp_b1     = (const float*)d_in[34];
  const float* pp2_w     = (const float*)d_in[35];
  const float* pp2_b     = (const float*)d_in[36];
  const float* al_w      = (const float*)d_in[37];
  const float* al_b      = (const float*)d_in[38];
  const float* alpha_aux = (const float*)d_in[39];
  const float* en_w      = (const float*)d_in[40];
  const float* en_b      = (const float*)d_in[41];
  const float* sf1_w     = (const float*)d_in[42];
  const float* sf_g1     = (const float*)d_in[43];
  const float* sf_b1     = (const float*)d_in[44];
  const float* sf2_w     = (const float*)d_in[45];
  const float* sf_g2     = (const float*)d_in[46];
  const float* sf_b2     = (const float*)d_in[47];
  const float* sf3_w     = (const float*)d_in[48];
  const float* sf3_b     = (const float*)d_in[49];
  const float* tm_w      = (const float*)d_in[50];
  const float* tm_b      = (const float*)d_in[51];
  const float* ph_w      = (const float*)d_in[52];
  const float* ph_b      = (const float*)d_in[53];
  float* out = (float*)d_out;

  float* W = (float*)d_ws;
  size_t off = 0;
  auto alloc = [&](size_t n){ float* p = W + off; off += n; return p; };
  float* glob    = alloc(512);
  float* tt      = alloc(2048);
  float* tms     = alloc(1024);
  float* ln1     = alloc(16);
  float* ln2     = alloc(16);
  float* lnpart  = alloc(2048);      // 512 × double2 partials (8-byte aligned: off is even)
  float* gn1     = alloc(512);
  float* gn2     = alloc(512);
  float* gn3     = alloc(512);
  float* gn4     = alloc(512);
  float* dS      = alloc(8192);
  float* dL      = alloc(8192);
  float* eB      = alloc(8192);
  float* w_inT   = alloc(16384);
  float* wT4     = alloc(147456);    // 4 transposed conv weights [64][576]
  float* sf1Wp   = alloc(8192);      // [64][128]
  float* sf1dot  = alloc(128);       // dot1|dot2
  float* cbn     = alloc(524288);    // cond_feat+glob, NHWC [8192][64]
  float* xgate   = alloc(1048576);   // NHWC [8192][128]; later reused as xmod
  float* xss     = alloc(1048576);   // NHWC [8192][128]; later reused as xo
  float* seq_x   = alloc(4194304);   // later: mamba_out
  float* xm_pre  = alloc(8388608);   // later: y (scanC out)
  float* z_silu  = alloc(8388608);   // later: phb
  float* xm      = alloc(8388608);
  float* xdbl    = alloc(1310720);
  float* scr     = alloc(8388608);   // scans: Pb|Qb; physics: part|cat|hfn; MLP: hid|mo2
  float* xf      = alloc(1048576);   // NHWC [8192][128]
  float* fbuf    = alloc(524288);    // NHWC; later: act_n
  float* actb    = alloc(524288);    // NHWC
  float* sbuf    = alloc(524288);    // NHWC
  float* s2buf   = alloc(524288);    // NHWC
  float* dseed   = alloc(524288);    // NHWC
  float* xxb     = alloc(524288);
  if (ws_size < off*sizeof(float)) return;

  // aliases (stream-order lifetimes verified)
  double* lnps     = (double*)lnpart;
  float* Pb        = scr;               // scans phase: 1024 blk × 256 × 16 = 4M floats
  float* Qb        = scr + 4194304;
  float* yscan     = xm_pre;            // after conv1d
  float* mamba_out = seq_x;             // after scanC (seq dead post in_proj)
  float* phb       = z_silu;            // after scanC (z dead)
  float* xmod      = xgate;             // after k_fuse
  float* xo        = xss;               // after k_dwconv
  float* act_n     = fbuf;              // after gn1 apply consumed
  float* part      = scr;               // physics phase (scans done)
  float* cat       = scr + 1572864;     // [8192][128]: phys | learned
  float* hfn       = scr + 2621440;     // cond_hf NHWC
  float* hid       = scr;               // MLP phase
  float* mo2       = scr + 2097152;

  // ---- main path ----
  k_small3<<<896,256,0,stream>>>(gtok, ttok, w_glob, b_glob, w_ssmt, b_ssmt, tm_w, tm_b, glob, tt, tms);
  k_wT<<<64,256,0,stream>>>(w_in, w_inT);
  k_ln_part<<<512,256,0,stream>>>(x, lnps);
  k_ln_fin<<<8,64,0,stream>>>(lnps, ln1, 1e-6f);
  k_xp<<<512,256,0,stream>>>(x, cond_base, ln1, glob, w_inT, b_in, gamma_gate, xss, xgate, cbn);
  k_dwconv<<<4096,256,0,stream>>>(xss, w_dw, b_dw, cbn, tt, gamma_main, seq_x);
  gemm_in<<<dim3(8,512),256,0,stream>>>(seq_x, m_in_w, xm_pre, z_silu);
  k_conv1d<<<32768,256,0,stream>>>(xm_pre, m_conv_w, m_conv_b, xm);
  gemm_nt<0><<<dim3(1,512),256,0,stream>>>(xm, m_xproj_w, nullptr, xdbl, 32768, 40, 256);
  k_scanA<<<1024,256,0,stream>>>(xm, xdbl, m_dt_w, m_dt_b, m_Alog, Pb, Qb);
  k_scanC<<<1024,256,0,stream>>>(xm, xdbl, m_dt_w, m_dt_b, m_Alog, Pb, Qb, m_D, z_silu, yscan);
  gemm_nt<0><<<dim3(2,512),256,0,stream>>>(yscan, m_out_w, nullptr, mamba_out, 32768, 128, 256);
  k_fuse<<<4096,256,0,stream>>>(mamba_out, xgate, xf);

  // ---- physics path (NHWC; scr reused as part/cat/hfn after scans) ----
  k_phys1<<<8,256,0,stream>>>(pan_raw, dS, dL, eB);
  k_wconvT<<<576,256,0,stream>>>(pp2_w, al_w, sf2_w, sf3_w, wT4);
  k_sf1prep<<<1,256,0,stream>>>(sf1_w, en_w, en_b, alpha_aux, sf1Wp, sf1dot);
  k_hfT<<<2048,256,0,stream>>>(cond_hf, hfn);
  k_conv_pp1_n<<<2048,256,0,stream>>>(dS, dL, pp1_w, pp1_b, fbuf);
  k_gn_stats_n<<<256,256,0,stream>>>(fbuf, gn1, 1e-5f);
  k_gn_apply_n<<<2048,256,0,stream>>>(fbuf, gn1, pp_g1, pp_b1, actb);
  k_conv_gemm<<<dim3(3,128),256,0,stream>>>(actb, wT4, part);
  k_conv_red<<<2048,256,0,stream>>>(part, pp2_b, nullptr, 0, cat, 128);          // physf -> cat[:,0:64]
  k_conv_gemm<<<dim3(3,128),256,0,stream>>>(hfn, wT4 + 36864, part);
  k_conv_red<<<2048,256,0,stream>>>(part, al_b, nullptr, 0, cat + 64, 128);      // learned -> cat[:,64:128]
  gemm_sfuse<<<128,256,0,stream>>>(cat, sf1Wp, eB, sf1dot, sbuf);
  k_gn_stats_n<<<256,256,0,stream>>>(sbuf, gn2, 1e-5f);
  k_gn_apply_n<<<2048,256,0,stream>>>(sbuf, gn2, sf_g1, sf_b1, actb);
  k_conv_gemm<<<dim3(3,128),256,0,stream>>>(actb, wT4 + 2*36864, part);
  k_conv_red<<<2048,256,0,stream>>>(part, nullptr, nullptr, 0, s2buf, 64);
  k_gn_stats_n<<<256,256,0,stream>>>(s2buf, gn3, 1e-5f);
  k_gn_apply_n<<<2048,256,0,stream>>>(s2buf, gn3, sf_g2, sf_b2, actb);
  k_conv_gemm<<<dim3(3,128),256,0,stream>>>(actb, wT4 + 3*36864, part);
  k_conv_red<<<2048,256,0,stream>>>(part, sf3_b, cat, 128, dseed, 64);           // + physf resid
  k_gn_stats_n<<<256,256,0,stream>>>(dseed, gn4, 1e-5f);
  k_apply_a_n<<<2048,256,0,stream>>>(dseed, gn4, tms, act_n);
  gemm_nt<0><<<dim3(6,128),256,0,stream>>>(act_n, ph_w, ph_b, phb, 8192, 384, 64);

  // ---- merge + output projection + MLP ----
  k_xmod<<<4096,256,0,stream>>>(xf, phb, xmod);
  gemm_nt<0><<<dim3(1,128),256,0,stream>>>(xmod, w_out, b_out, xo, 8192, 64, 128);
  k_opj_epi<<<2048,256,0,stream>>>(xo, x, cond_base, xxb);
  k_ln_part<<<512,256,0,stream>>>(xxb, lnps);
  k_ln_fin<<<8,64,0,stream>>>(lnps, ln2, 1e-6f);
  gemm_fc1<<<dim3(4,128),256,0,stream>>>(xxb, cond_base, ln2, w_fc1, b_fc1, hid);
  gemm_nt<0><<<dim3(1,128),256,0,stream>>>(hid, w_fc2, b_fc2, mo2, 8192, 64, 256);
  k_mlp_epi<<<2048,256,0,stream>>>(mo2, xxb, cond_base, out);

  (void)in_sizes; (void)n_in; (void)out_size;
}

// Round 13
// 820.522 us; speedup vs baseline: 1.0872x; 1.0872x over previous
//
#include <hip/hip_runtime.h>
#include <math.h>

#define CDIV(a,b) (((a)+(b)-1)/(b))

__device__ __forceinline__ float siluf(float x){ return x/(1.f+__expf(-x)); }
__device__ __forceinline__ float sigmoidf_(float x){ return 1.f/(1.f+__expf(-x)); }
__device__ __forceinline__ float softplusf(float x){ return x>20.f ? x : log1pf(__expf(x)); }
__device__ __forceinline__ float geluf(float x){ return 0.5f*x*(1.f+erff(x*0.70710678118654752440f)); }

// ---------------- small dense: glob, tt, tms (wave-reduced dots) ----------------
__global__ __launch_bounds__(256) void k_small3(
    const float* __restrict__ gtok, const float* __restrict__ ttok,
    const float* __restrict__ w_glob, const float* __restrict__ b_glob,
    const float* __restrict__ w_ssmt, const float* __restrict__ b_ssmt,
    const float* __restrict__ tm_w, const float* __restrict__ tm_b,
    float* __restrict__ glob, float* __restrict__ tt, float* __restrict__ tms)
{
  int g = blockIdx.x*4 + (threadIdx.x >> 6);
  int lane = threadIdx.x & 63;
  const float* w; const float* src; float bias; float* dst; bool dosilu;
  if (g < 512){
    int b = g >> 6, o = g & 63;
    w = w_glob + (size_t)o*256; src = gtok + (size_t)b*256; bias = b_glob[o]; dst = glob + g; dosilu = false;
  } else if (g < 2560){
    int gg = g - 512; int b = gg >> 8, o = gg & 255;
    w = w_ssmt + (size_t)o*256; src = ttok + (size_t)b*256; bias = b_ssmt[o]; dst = tt + gg; dosilu = true;
  } else {
    int gg = g - 2560; int b = gg >> 7, o = gg & 127;
    w = tm_w + (size_t)o*256; src = ttok + (size_t)b*256; bias = tm_b[o]; dst = tms + gg; dosilu = true;
  }
  float acc = 0.f;
  for (int k = lane; k < 256; k += 64){
    float sv = src[k];
    if (dosilu) sv = siluf(sv);
    acc += sv * w[k];
  }
  acc += __shfl_xor(acc, 1);
  acc += __shfl_xor(acc, 2);
  acc += __shfl_xor(acc, 4);
  acc += __shfl_xor(acc, 8);
  acc += __shfl_xor(acc, 16);
  acc += __shfl_xor(acc, 32);
  if (lane == 0) *dst = acc + bias;
}

// ---------------- transpose w_in [256][64] -> w_inT [64][256] ----------------
__global__ __launch_bounds__(256) void k_wT(const float* __restrict__ w_in, float* __restrict__ w_inT)
{
  int i = blockIdx.x*256 + threadIdx.x;
  if (i >= 16384) return;
  int o = i & 255, k = i >> 8;
  w_inT[k*256 + o] = w_in[o*64 + k];
}

// ---------------- conv weights [64][64][3][3] -> wT[conv][oc][tap*64+ic] ----------------
__global__ __launch_bounds__(256) void k_wconvT(
    const float* __restrict__ w0, const float* __restrict__ w1,
    const float* __restrict__ w2, const float* __restrict__ w3, float* __restrict__ wT4)
{
  int i = blockIdx.x*256 + threadIdx.x;
  if (i >= 4*36864) return;
  int conv = i / 36864; int rem = i % 36864;
  int oc = rem / 576; int k = rem % 576;
  int tap = k >> 6; int ic = k & 63;
  const float* src = conv==0 ? w0 : conv==1 ? w1 : conv==2 ? w2 : w3;
  wT4[i] = src[(size_t)(oc*64+ic)*9 + tap];
}

// ---------------- cond_hf NCHW -> NHWC ----------------
__global__ __launch_bounds__(256) void k_hfT(const float* __restrict__ in, float* __restrict__ out)
{
  int i = blockIdx.x*256 + threadIdx.x;
  if (i >= 524288) return;
  int c = i & 63; int px = i >> 6; int b = px >> 10, hw = px & 1023;
  out[i] = in[((size_t)(b*64+c))*1024 + hw];
}

// ---------------- sf1 prep: Wp=[w_p | beta*w_l], dot1/dot2 from energy branch ----------------
__global__ __launch_bounds__(256) void k_sf1prep(
    const float* __restrict__ sf1_w, const float* __restrict__ en_w, const float* __restrict__ en_b,
    const float* __restrict__ alpha, float* __restrict__ Wp, float* __restrict__ dot12)
{
  float beta = tanhf(alpha[0]);
  int tid = threadIdx.x;
  for (int i = tid; i < 8192; i += 256){
    int o = i >> 7, c = i & 127;
    float v = sf1_w[(size_t)o*192 + c];
    Wp[i] = (c < 64) ? v : beta*v;
  }
  if (tid < 128){
    int o = tid & 63; bool second = tid >= 64;
    float acc = 0.f;
    for (int c2 = 0; c2 < 64; c2++){
      float wv = sf1_w[(size_t)o*192 + 128 + c2];
      acc += wv * (second ? en_b[c2] : en_w[c2]);
    }
    dot12[tid] = acc;
  }
}

// ---------------- LN stage 1: partial sums, 64 blocks per batch ----------------
__global__ __launch_bounds__(256) void k_ln_part(const float* __restrict__ x, double* __restrict__ ps)
{
  int blk = blockIdx.x;                 // 0..511, batch = blk>>6
  int tid = threadIdx.x;
  const float4 v = *(const float4*)(x + (size_t)blk*1024 + tid*4);
  double s  = (double)v.x + (double)v.y + (double)v.z + (double)v.w;
  double ss = (double)v.x*v.x + (double)v.y*v.y + (double)v.z*v.z + (double)v.w*v.w;
  __shared__ double rs[256], rss[256];
  rs[tid] = s; rss[tid] = ss; __syncthreads();
  for (int o = 128; o > 0; o >>= 1){ if (tid < o){ rs[tid]+=rs[tid+o]; rss[tid]+=rss[tid+o]; } __syncthreads(); }
  if (tid == 0){ ps[blk*2] = rs[0]; ps[blk*2+1] = rss[0]; }
}

// ---------------- LN stage 2: fold 64 partials per batch -> mean/rstd ----------------
__global__ __launch_bounds__(64) void k_ln_fin(const double* __restrict__ ps, float* __restrict__ st, float eps)
{
  int b = blockIdx.x; int t = threadIdx.x;
  double s  = ps[(b*64+t)*2];
  double ss = ps[(b*64+t)*2+1];
  for (int o = 32; o > 0; o >>= 1){
    s  += __shfl_xor(s,  o);
    ss += __shfl_xor(ss, o);
  }
  if (t == 0){
    double m = s/65536.0, var = ss/65536.0 - m*m;
    st[b*2] = (float)m; st[b*2+1] = (float)(1.0/sqrt(var + (double)eps));
  }
}

// ---------------- x_norm -> xp = @ w_in.T ; NHWC outputs ----------------
__global__ __launch_bounds__(256) void k_xp(
    const float* __restrict__ x, const float* __restrict__ cond,
    const float* __restrict__ ln, const float* __restrict__ glob,
    const float* __restrict__ w_inT, const float* __restrict__ b_in,
    const float* __restrict__ gamma_gate,
    float* __restrict__ xss, float* __restrict__ xgate, float* __restrict__ cbn)
{
  int p0 = blockIdx.x * 16;
  int tid = threadIdx.x;
  __shared__ float xv[64*16];   // [c][p]
  __shared__ float cf[64*16];   // [c][p] cond_feat+glob
  for (int i = tid; i < 1024; i += 256){
    int c = i >> 4, p = i & 15;
    int pix = p0 + p; int b = pix >> 10, hw = pix & 1023;
    float mean = ln[b*2], rstd = ln[b*2+1];
    float v  = x[((size_t)(b*64+c))*1024 + hw];
    float sc = cond[((size_t)(b*512+64+c))*1024 + hw];
    float sh = cond[((size_t)(b*512+c))*1024 + hw];
    xv[c*16+p] = ((v-mean)*rstd)*(1.f+sc)+sh;
    cf[c*16+p] = cond[((size_t)(b*512+384+c))*1024 + hw] + glob[b*64+c];
  }
  __syncthreads();
  int o = tid;
  float acc[16];
  float bi = b_in[o];
  #pragma unroll
  for (int p = 0; p < 16; p++) acc[p] = bi;
  for (int k = 0; k < 64; k++){
    float wv = w_inT[k*256 + o];
    #pragma unroll
    for (int p = 0; p < 16; p++) acc[p] = fmaf(xv[k*16+p], wv, acc[p]);
  }
  float gg = gamma_gate[0];
  #pragma unroll
  for (int p = 0; p < 16; p++){
    int pix = p0 + p;
    if (o < 128){
      xss[(size_t)pix*128 + o] = acc[p];
    } else {
      int c = o - 128;
      float cb = cf[(c&63)*16+p];
      float g = acc[p] + gg*cb;
      xgate[(size_t)pix*128 + c] = siluf(g);
      if (c < 64) cbn[(size_t)pix*64 + c] = cb;
    }
  }
}

// ---------------- depthwise 3x3 conv + silu + ssm modulation + 4-dir scatter (NHWC) ----------------
__global__ __launch_bounds__(256) void k_dwconv(
    const float* __restrict__ xss, const float* __restrict__ w_dw, const float* __restrict__ b_dw,
    const float* __restrict__ cbn, const float* __restrict__ tt, const float* __restrict__ gamma_main,
    float* __restrict__ seq_x)
{
  int i = blockIdx.x*256 + threadIdx.x;
  if (i >= 8*1024*128) return;
  int c = i & 127; int pix = i >> 7;
  int b = pix >> 10, hw = pix & 1023;
  int h = hw >> 5, w = hw & 31;
  float acc = b_dw[c];
  const float* wp = w_dw + c*9;
  const float* src = xss + ((size_t)b*1024)*128;
  #pragma unroll
  for (int ky = 0; ky < 3; ky++){
    int y = h + ky - 1; if (y < 0 || y > 31) continue;
    #pragma unroll
    for (int kx = 0; kx < 3; kx++){
      int xw = w + kx - 1; if (xw < 0 || xw > 31) continue;
      acc += src[(size_t)(y*32+xw)*128 + c]*wp[ky*3+kx];
    }
  }
  float v = siluf(acc);
  float cb = cbn[(size_t)pix*64 + (c&63)];
  v = (v + gamma_main[0]*cb)*(1.f+tt[b*256+c]) + tt[b*256+128+c];
  int l3 = w*32 + h;
  seq_x[(((size_t)b*1024)      + hw       )*128 + c] = v;
  seq_x[(((size_t)(8+b)*1024)  + (1023-hw))*128 + c] = v;
  seq_x[(((size_t)(16+b)*1024) + l3       )*128 + c] = v;
  seq_x[(((size_t)(24+b)*1024) + (1023-l3))*128 + c] = v;
}

// ---------------- generic fp32 GEMM: C[M,N] = act(A[M,K] @ W[N,K]^T + bias) ----------------
template<int ACT>  // 0 none, 1 silu
__global__ __launch_bounds__(256) void gemm_nt(
    const float* __restrict__ A, const float* __restrict__ W, const float* __restrict__ bias,
    float* __restrict__ C, int M, int N, int K)
{
  __shared__ float As[16][68];
  __shared__ float Ws[16][68];
  int bm = blockIdx.y*64, bn = blockIdx.x*64;
  int tid = threadIdx.x;
  int tm = (tid >> 4) << 2;
  int tn = (tid & 15) << 2;
  float acc[4][4] = {};
  for (int k0 = 0; k0 < K; k0 += 16){
    #pragma unroll
    for (int i = 0; i < 4; i++){
      int idx = tid + 256*i;
      int r = idx >> 4, cc = idx & 15;
      int gm = bm + r;
      As[cc][r] = (gm < M) ? A[(size_t)gm*K + k0 + cc] : 0.f;
      int gn = bn + r;
      Ws[cc][r] = (gn < N) ? W[(size_t)gn*K + k0 + cc] : 0.f;
    }
    __syncthreads();
    #pragma unroll
    for (int kk = 0; kk < 16; kk++){
      float a[4], w[4];
      #pragma unroll
      for (int i = 0; i < 4; i++) a[i] = As[kk][tm+i];
      #pragma unroll
      for (int j = 0; j < 4; j++) w[j] = Ws[kk][tn+j];
      #pragma unroll
      for (int i = 0; i < 4; i++)
        #pragma unroll
        for (int j = 0; j < 4; j++) acc[i][j] = fmaf(a[i], w[j], acc[i][j]);
    }
    __syncthreads();
  }
  #pragma unroll
  for (int i = 0; i < 4; i++){
    int gm = bm + tm + i; if (gm >= M) continue;
    #pragma unroll
    for (int j = 0; j < 4; j++){
      int gn = bn + tn + j; if (gn >= N) continue;
      float v = acc[i][j] + (bias ? bias[gn] : 0.f);
      if (ACT == 1) v = siluf(v);
      C[(size_t)gm*N + gn] = v;
    }
  }
}

// ---------------- fused in_proj GEMM: both halves, A read once ----------------
__global__ __launch_bounds__(256) void gemm_in(
    const float* __restrict__ A, const float* __restrict__ W,
    float* __restrict__ Cx, float* __restrict__ Cz)
{
  __shared__ float As[16][68];
  __shared__ float Ws[16][68];
  int bm = blockIdx.y*64, bn = blockIdx.x*64;   // N total 512
  int tid = threadIdx.x;
  int tm = (tid >> 4) << 2;
  int tn = (tid & 15) << 2;
  float acc[4][4] = {};
  for (int k0 = 0; k0 < 128; k0 += 16){
    #pragma unroll
    for (int i = 0; i < 4; i++){
      int idx = tid + 256*i;
      int r = idx >> 4, cc = idx & 15;
      As[cc][r] = A[(size_t)(bm+r)*128 + k0 + cc];
      Ws[cc][r] = W[(size_t)(bn+r)*128 + k0 + cc];
    }
    __syncthreads();
    #pragma unroll
    for (int kk = 0; kk < 16; kk++){
      float a[4], w[4];
      #pragma unroll
      for (int i = 0; i < 4; i++) a[i] = As[kk][tm+i];
      #pragma unroll
      for (int j = 0; j < 4; j++) w[j] = Ws[kk][tn+j];
      #pragma unroll
      for (int i = 0; i < 4; i++)
        #pragma unroll
        for (int j = 0; j < 4; j++) acc[i][j] = fmaf(a[i], w[j], acc[i][j]);
    }
    __syncthreads();
  }
  #pragma unroll
  for (int i = 0; i < 4; i++){
    int gm = bm + tm + i;
    #pragma unroll
    for (int j = 0; j < 4; j++){
      int gn = bn + tn + j;
      float v = acc[i][j];
      if (gn < 256) Cx[(size_t)gm*256 + gn] = v;
      else          Cz[(size_t)gm*256 + gn - 256] = siluf(v);
    }
  }
}

// ---------------- implicit-GEMM 3x3 conv (NHWC, K split by ky) ----------------
// A: [8192][64] NHWC. wT: [64][576] (tap-major k). part: [3][8192][64].
__global__ __launch_bounds__(256) void k_conv_gemm(
    const float* __restrict__ A, const float* __restrict__ wT, float* __restrict__ part)
{
  __shared__ float As[16][68];
  __shared__ float Ws[16][68];
  int kc = blockIdx.x;                // ky chunk 0..2
  int bm = blockIdx.y*64;
  int tid = threadIdx.x;
  int tm = (tid >> 4) << 2;
  int tn = (tid & 15) << 2;
  int dy = kc - 1;
  float acc[4][4] = {};
  for (int k0 = 0; k0 < 192; k0 += 16){
    int j  = k0 >> 6;                 // kx index (16 | 64 so single tap per k0 block)
    int ic0 = k0 & 63;
    int dx = j - 1;
    #pragma unroll
    for (int i = 0; i < 4; i++){
      int idx = tid + 256*i;
      int r = idx >> 4, kk = idx & 15;
      int gm = bm + r;
      int hw = gm & 1023;
      int h = hw >> 5, w = hw & 31;
      int hh = h + dy, ww = w + dx;
      bool ok = (hh >= 0) && (hh < 32) && (ww >= 0) && (ww < 32);
      As[kk][r] = ok ? A[(size_t)(gm + dy*32 + dx)*64 + ic0 + kk] : 0.f;
      Ws[kk][r] = wT[(size_t)r*576 + kc*192 + k0 + kk];
    }
    __syncthreads();
    #pragma unroll
    for (int kk = 0; kk < 16; kk++){
      float a[4], w4[4];
      #pragma unroll
      for (int i = 0; i < 4; i++) a[i] = As[kk][tm+i];
      #pragma unroll
      for (int jj = 0; jj < 4; jj++) w4[jj] = Ws[kk][tn+jj];
      #pragma unroll
      for (int i = 0; i < 4; i++)
        #pragma unroll
        for (int jj = 0; jj < 4; jj++) acc[i][jj] = fmaf(a[i], w4[jj], acc[i][jj]);
    }
    __syncthreads();
  }
  float* dst = part + ((size_t)kc*8192 + bm)*64;
  #pragma unroll
  for (int i = 0; i < 4; i++)
    #pragma unroll
    for (int jj = 0; jj < 4; jj++)
      dst[(size_t)(tm+i)*64 + tn+jj] = acc[i][jj];
}

// ---------------- conv partial reduce + bias + resid ----------------
__global__ __launch_bounds__(256) void k_conv_red(
    const float* __restrict__ part, const float* __restrict__ bias,
    const float* __restrict__ resid, int residLd,
    float* __restrict__ out, int outLd)
{
  int i = blockIdx.x*256 + threadIdx.x;
  if (i >= 524288) return;
  int oc = i & 63; int px = i >> 6;
  float v = part[i] + part[524288 + i] + part[1048576 + i];
  if (bias) v += bias[oc];
  if (resid) v += resid[(size_t)px*residLd + oc];
  out[(size_t)px*outLd + oc] = v;
}

// ---------------- sfuse GEMM: C = cat[8192][128] @ Wp[64][128]^T + e*dot1 + dot2 ----------------
__global__ __launch_bounds__(256) void gemm_sfuse(
    const float* __restrict__ A, const float* __restrict__ Wp,
    const float* __restrict__ eB, const float* __restrict__ dot12,
    float* __restrict__ C)
{
  __shared__ float As[16][68];
  __shared__ float Ws[16][68];
  int bm = blockIdx.x*64;
  int tid = threadIdx.x;
  int tm = (tid >> 4) << 2;
  int tn = (tid & 15) << 2;
  float acc[4][4] = {};
  for (int k0 = 0; k0 < 128; k0 += 16){
    #pragma unroll
    for (int i = 0; i < 4; i++){
      int idx = tid + 256*i;
      int r = idx >> 4, cc = idx & 15;
      As[cc][r] = A[(size_t)(bm+r)*128 + k0 + cc];
      Ws[cc][r] = Wp[(size_t)r*128 + k0 + cc];
    }
    __syncthreads();
    #pragma unroll
    for (int kk = 0; kk < 16; kk++){
      float a[4], w[4];
      #pragma unroll
      for (int i = 0; i < 4; i++) a[i] = As[kk][tm+i];
      #pragma unroll
      for (int j = 0; j < 4; j++) w[j] = Ws[kk][tn+j];
      #pragma unroll
      for (int i = 0; i < 4; i++)
        #pragma unroll
        for (int j = 0; j < 4; j++) acc[i][j] = fmaf(a[i], w[j], acc[i][j]);
    }
    __syncthreads();
  }
  #pragma unroll
  for (int i = 0; i < 4; i++){
    int gm = bm + tm + i;
    float e = eB[gm];
    #pragma unroll
    for (int j = 0; j < 4; j++){
      int gn = tn + j;
      C[(size_t)gm*64 + gn] = acc[i][j] + e*dot12[gn] + dot12[64+gn];
    }
  }
}

// ---------------- causal depthwise conv1d (k=4) + silu ----------------
__global__ __launch_bounds__(256) void k_conv1d(
    const float* __restrict__ xin, const float* __restrict__ w, const float* __restrict__ bias,
    float* __restrict__ out)
{
  int i = blockIdx.x*256 + threadIdx.x;
  if (i >= 32*1024*256) return;
  int d = i & 255; int l = (i >> 8) & 1023; int b = i >> 18;
  const float* base = xin + ((size_t)b*1024)*256 + d;
  float acc = bias[d];
  const float* wp = w + d*4;
  #pragma unroll
  for (int k = 0; k < 4; k++){
    int ll = l - 3 + k;
    if (ll >= 0) acc += base[(size_t)ll*256]*wp[k];
  }
  out[i] = siluf(acc);
}

// ---------------- chunked scan, phase A (dt fused inline), 32 chunks x 32 steps ----------------
__global__ __launch_bounds__(256) void k_scanA(
    const float* __restrict__ xm, const float* __restrict__ xdbl,
    const float* __restrict__ dtw, const float* __restrict__ dtb,
    const float* __restrict__ Alog, float* __restrict__ Pb, float* __restrict__ Qb)
{
  int bb = blockIdx.x >> 5, ch = blockIdx.x & 31;
  int d = threadIdx.x;
  float an[16];
  {
    const float4* a4 = (const float4*)(Alog + d*16);
    #pragma unroll
    for (int j = 0; j < 4; j++){
      float4 t = a4[j];
      an[4*j+0] = -__expf(t.x); an[4*j+1] = -__expf(t.y); an[4*j+2] = -__expf(t.z); an[4*j+3] = -__expf(t.w);
    }
  }
  float w8[8];
  {
    const float4* w4 = (const float4*)(dtw + d*8);
    float4 a = w4[0], b2 = w4[1];
    w8[0]=a.x; w8[1]=a.y; w8[2]=a.z; w8[3]=a.w; w8[4]=b2.x; w8[5]=b2.y; w8[6]=b2.z; w8[7]=b2.w;
  }
  float dtb_d = dtb[d];
  float P[16], Q[16];
  #pragma unroll
  for (int n = 0; n < 16; n++){ P[n] = 1.f; Q[n] = 0.f; }
  int m0 = bb*1024 + ch*32;
  for (int s = 0; s < 32; s++){
    int m = m0 + s;
    const float4* X4 = (const float4*)(xdbl + (size_t)m*40);
    float4 x0 = X4[0], x1 = X4[1];
    float t = dtb_d;
    t = fmaf(x0.x,w8[0],t); t = fmaf(x0.y,w8[1],t); t = fmaf(x0.z,w8[2],t); t = fmaf(x0.w,w8[3],t);
    t = fmaf(x1.x,w8[4],t); t = fmaf(x1.y,w8[5],t); t = fmaf(x1.z,w8[6],t); t = fmaf(x1.w,w8[7],t);
    float dtv = softplusf(t);
    float xv  = xm[(size_t)m*256 + d];
    const float4* B4 = (const float4*)(xdbl + (size_t)m*40 + 8);
    float Bv[16];
    #pragma unroll
    for (int j = 0; j < 4; j++){ float4 tt2 = B4[j]; Bv[4*j]=tt2.x; Bv[4*j+1]=tt2.y; Bv[4*j+2]=tt2.z; Bv[4*j+3]=tt2.w; }
    float dx = dtv*xv;
    #pragma unroll
    for (int n = 0; n < 16; n++){
      float a = __expf(dtv*an[n]);
      Q[n] = fmaf(a, Q[n], dx*Bv[n]);
      P[n] *= a;
    }
  }
  size_t base = ((size_t)(blockIdx.x*256 + d))*16;
  float4* p4 = (float4*)(Pb + base);
  float4* q4 = (float4*)(Qb + base);
  #pragma unroll
  for (int j = 0; j < 4; j++){
    p4[j] = make_float4(P[4*j], P[4*j+1], P[4*j+2], P[4*j+3]);
    q4[j] = make_float4(Q[4*j], Q[4*j+1], Q[4*j+2], Q[4*j+3]);
  }
}

// ---------------- scan middle: exclusive prefix over 32 chunks; H overwrites Pb in place ----------------
// grid (4, 32): blockIdx.y = bb, d = blockIdx.x*64 + tid. Per thread: 16 indep state chains.
__global__ __launch_bounds__(64) void k_scanM(float* __restrict__ Pb, const float* __restrict__ Qb)
{
  int bb = blockIdx.y;
  int d = blockIdx.x*64 + threadIdx.x;
  float h[16];
  #pragma unroll
  for (int n = 0; n < 16; n++) h[n] = 0.f;
  for (int ch = 0; ch < 32; ch++){
    size_t base = ((size_t)((bb*32+ch)*256 + d))*16;
    float4* p4 = (float4*)(Pb + base);
    const float4* q4 = (const float4*)(Qb + base);
    #pragma unroll
    for (int j = 0; j < 4; j++){
      float4 p = p4[j]; float4 q = q4[j];
      p4[j] = make_float4(h[4*j], h[4*j+1], h[4*j+2], h[4*j+3]);   // exclusive prefix out
      h[4*j+0] = fmaf(p.x, h[4*j+0], q.x);
      h[4*j+1] = fmaf(p.y, h[4*j+1], q.y);
      h[4*j+2] = fmaf(p.z, h[4*j+2], q.z);
      h[4*j+3] = fmaf(p.w, h[4*j+3], q.w);
    }
  }
}

// ---------------- chunked scan, phase C: load prefix, rescan (dt inline), fused ymod ----------------
__global__ __launch_bounds__(256) void k_scanC(
    const float* __restrict__ xm, const float* __restrict__ xdbl,
    const float* __restrict__ dtw, const float* __restrict__ dtb,
    const float* __restrict__ Alog, const float* __restrict__ Hb,
    const float* __restrict__ Dw, const float* __restrict__ zsilu, float* __restrict__ yout)
{
  int bb = blockIdx.x >> 5, ch = blockIdx.x & 31;
  int d = threadIdx.x;
  float an[16];
  {
    const float4* a4 = (const float4*)(Alog + d*16);
    #pragma unroll
    for (int j = 0; j < 4; j++){
      float4 t = a4[j];
      an[4*j+0] = -__expf(t.x); an[4*j+1] = -__expf(t.y); an[4*j+2] = -__expf(t.z); an[4*j+3] = -__expf(t.w);
    }
  }
  float w8[8];
  {
    const float4* w4 = (const float4*)(dtw + d*8);
    float4 a = w4[0], b2 = w4[1];
    w8[0]=a.x; w8[1]=a.y; w8[2]=a.z; w8[3]=a.w; w8[4]=b2.x; w8[5]=b2.y; w8[6]=b2.z; w8[7]=b2.w;
  }
  float dtb_d = dtb[d];
  float h[16];
  {
    size_t base = ((size_t)(blockIdx.x*256 + d))*16;
    const float4* hp = (const float4*)(Hb + base);
    #pragma unroll
    for (int j = 0; j < 4; j++){
      float4 hh = hp[j];
      h[4*j+0] = hh.x; h[4*j+1] = hh.y; h[4*j+2] = hh.z; h[4*j+3] = hh.w;
    }
  }
  float Dd = Dw[d];
  int m0 = bb*1024 + ch*32;
  for (int s = 0; s < 32; s++){
    int m = m0 + s;
    const float4* X4 = (const float4*)(xdbl + (size_t)m*40);
    float4 x0 = X4[0], x1 = X4[1];
    float t = dtb_d;
    t = fmaf(x0.x,w8[0],t); t = fmaf(x0.y,w8[1],t); t = fmaf(x0.z,w8[2],t); t = fmaf(x0.w,w8[3],t);
    t = fmaf(x1.x,w8[4],t); t = fmaf(x1.y,w8[5],t); t = fmaf(x1.z,w8[6],t); t = fmaf(x1.w,w8[7],t);
    float dtv = softplusf(t);
    float xv  = xm[(size_t)m*256 + d];
    const float4* B4 = (const float4*)(xdbl + (size_t)m*40 + 8);
    const float4* C4 = (const float4*)(xdbl + (size_t)m*40 + 24);
    float Bv[16], Cv[16];
    #pragma unroll
    for (int j = 0; j < 4; j++){
      float4 tt2 = B4[j]; Bv[4*j]=tt2.x; Bv[4*j+1]=tt2.y; Bv[4*j+2]=tt2.z; Bv[4*j+3]=tt2.w;
      float4 u = C4[j]; Cv[4*j]=u.x; Cv[4*j+1]=u.y; Cv[4*j+2]=u.z; Cv[4*j+3]=u.w;
    }
    float dx = dtv*xv;
    float y = 0.f;
    #pragma unroll
    for (int n = 0; n < 16; n++){
      float a = __expf(dtv*an[n]);
      h[n] = fmaf(a, h[n], dx*Bv[n]);
      y = fmaf(h[n], Cv[n], y);
    }
    float z = zsilu[(size_t)m*256 + d];
    yout[(size_t)m*256 + d] = (y + xv*Dd)*z;
  }
}

// ---------------- gather 4 directions + gate (NHWC) ----------------
__global__ __launch_bounds__(256) void k_fuse(
    const float* __restrict__ mo, const float* __restrict__ xgate, float* __restrict__ xf)
{
  int i = blockIdx.x*256 + threadIdx.x;
  if (i >= 8*1024*128) return;
  int c = i & 127; int pix = i >> 7;
  int b = pix >> 10, hw = pix & 1023;
  int h = hw >> 5, w = hw & 31; int l3 = w*32 + h;
  float o1 = mo[(((size_t)b*1024)      + hw       )*128 + c];
  float o2 = mo[(((size_t)(8+b)*1024)  + (1023-hw))*128 + c];
  float o3 = mo[(((size_t)(16+b)*1024) + l3       )*128 + c];
  float o4 = mo[(((size_t)(24+b)*1024) + (1023-l3))*128 + c];
  xf[(size_t)pix*128 + c] = (o1+o2+o3+o4)*xgate[(size_t)pix*128 + c];
}

// ---------------- physics: blurs, diffs, std normalize, energy ----------------
__global__ __launch_bounds__(256) void k_phys1(
    const float* __restrict__ pan, float* __restrict__ dS, float* __restrict__ dL, float* __restrict__ eB)
{
  int b = blockIdx.x; int tid = threadIdx.x;
  __shared__ float tile[1024];
  __shared__ float ks[9];
  __shared__ float kl[25];
  __shared__ float red[256];
  __shared__ float sh_sig[2];
  __shared__ float sh_emax;
  for (int i = tid; i < 1024; i += 256) tile[i] = pan[b*1024+i];
  if (tid == 0){
    float s = 0;
    for (int j = 0; j < 3; j++) for (int i2 = 0; i2 < 3; i2++){
      float dy = (float)(j-1), dx = (float)(i2-1);
      float g = expf(-(dx*dx+dy*dy)*0.5f); ks[j*3+i2] = g; s += g;
    }
    for (int i2 = 0; i2 < 9; i2++) ks[i2] /= s;
    s = 0;
    for (int j = 0; j < 5; j++) for (int i2 = 0; i2 < 5; i2++){
      float dy = (float)(j-2), dx = (float)(i2-2);
      float g = expf(-(dx*dx+dy*dy)*0.125f); kl[j*5+i2] = g; s += g;
    }
    for (int i2 = 0; i2 < 25; i2++) kl[i2] /= s;
  }
  __syncthreads();
  float ds4[4], dl4[4], e4[4];
  float s_s = 0, ss_s = 0, s_l = 0, ss_l = 0;
  for (int j = 0; j < 4; j++){
    int px = tid + 256*j; int h = px >> 5, w = px & 31;
    float bs = 0;
    for (int ky = 0; ky < 3; ky++){
      int y = h + ky - 1; y = y < 0 ? -y : (y > 31 ? 62-y : y);
      for (int kx = 0; kx < 3; kx++){
        int xx = w + kx - 1; xx = xx < 0 ? -xx : (xx > 31 ? 62-xx : xx);
        bs += tile[y*32+xx]*ks[ky*3+kx];
      }
    }
    float bl = 0;
    for (int ky = 0; ky < 5; ky++){
      int y = h + ky - 2; y = y < 0 ? -y : (y > 31 ? 62-y : y);
      for (int kx = 0; kx < 5; kx++){
        int xx = w + kx - 2; xx = xx < 0 ? -xx : (xx > 31 ? 62-xx : xx);
        bl += tile[y*32+xx]*kl[ky*5+kx];
      }
    }
    float v = tile[px];
    float a = v - bs, c = v - bl;
    ds4[j] = a; dl4[j] = c;
    s_s += a; ss_s += a*a; s_l += c; ss_l += c*c;
  }
  #define BLK_RED(val, outvar) red[tid]=(val); __syncthreads(); \
    for (int o_=128;o_>0;o_>>=1){ if (tid<o_) red[tid]+=red[tid+o_]; __syncthreads(); } \
    float outvar = red[0]; __syncthreads();
  BLK_RED(s_s,  tot_s)
  BLK_RED(ss_s, tot_ss)
  BLK_RED(s_l,  tot_l)
  BLK_RED(ss_l, tot_ll)
  if (tid == 0){
    float var_s = (tot_ss - tot_s*tot_s/1024.f)/1023.f;
    float var_l = (tot_ll - tot_l*tot_l/1024.f)/1023.f;
    sh_sig[0] = sqrtf(var_s) + 1e-6f;
    sh_sig[1] = sqrtf(var_l) + 1e-6f;
  }
  __syncthreads();
  float inv_s = 1.f/sh_sig[0], inv_l = 1.f/sh_sig[1];
  float emax = 0;
  for (int j = 0; j < 4; j++){
    ds4[j] *= inv_s; dl4[j] *= inv_l;
    e4[j] = fabsf(ds4[j]) + fabsf(dl4[j]);
    emax = fmaxf(emax, e4[j]);
  }
  red[tid] = emax; __syncthreads();
  for (int o_ = 128; o_ > 0; o_ >>= 1){ if (tid < o_) red[tid] = fmaxf(red[tid], red[tid+o_]); __syncthreads(); }
  if (tid == 0) sh_emax = red[0];
  __syncthreads();
  float einv = 1.f/(sh_emax + 1e-6f);
  for (int j = 0; j < 4; j++){
    int px = tid + 256*j;
    dS[b*1024+px] = ds4[j];
    dL[b*1024+px] = dl4[j];
    eB[b*1024+px] = e4[j]*einv;
  }
}

// ---------------- pp1: conv 2->64, pad=1 (zeros), NHWC out ----------------
__global__ __launch_bounds__(256) void k_conv_pp1_n(
    const float* __restrict__ dS, const float* __restrict__ dL,
    const float* __restrict__ w, const float* __restrict__ bias, float* __restrict__ out)
{
  int i = blockIdx.x*256 + threadIdx.x;
  if (i >= 524288) return;
  int o = i & 63; int px = i >> 6;
  int b = px >> 10, hw = px & 1023;
  int h = hw >> 5, ww = hw & 31;
  float acc = bias[o];
  for (int ic = 0; ic < 2; ic++){
    const float* src = (ic ? dL : dS) + b*1024;
    const float* wp = w + (o*2+ic)*9;
    #pragma unroll
    for (int ky = 0; ky < 3; ky++){
      int y = h + ky - 1; if (y < 0 || y > 31) continue;
      #pragma unroll
      for (int kx = 0; kx < 3; kx++){
        int xx = ww + kx - 1; if (xx < 0 || xx > 31) continue;
        acc += src[y*32+xx]*wp[ky*3+kx];
      }
    }
  }
  out[i] = acc;
}

// ---------------- group-norm stats (NHWC, ld=64): block per (b,g) ----------------
__global__ __launch_bounds__(256) void k_gn_stats_n(const float* __restrict__ x, float* __restrict__ st, float eps)
{
  int blk = blockIdx.x; int tid = threadIdx.x;
  int b = blk >> 5, g = blk & 31;
  const float* p = x + (size_t)b*1024*64 + g*2;
  double s = 0.0, ss = 0.0;
  for (int px = tid; px < 1024; px += 256){
    float2 v = *(const float2*)(p + (size_t)px*64);
    s += v.x + v.y; ss += (double)v.x*v.x + (double)v.y*v.y;
  }
  __shared__ double rs[256], rss[256];
  rs[tid] = s; rss[tid] = ss; __syncthreads();
  for (int o = 128; o > 0; o >>= 1){ if (tid < o){ rs[tid]+=rs[tid+o]; rss[tid]+=rss[tid+o]; } __syncthreads(); }
  if (tid == 0){
    double m = rs[0]/2048.0, var = rss[0]/2048.0 - m*m;
    st[blk*2] = (float)m; st[blk*2+1] = (float)(1.0/sqrt(var + (double)eps));
  }
}

// ---------------- apply GN (affine) + silu (NHWC) ----------------
__global__ __launch_bounds__(256) void k_gn_apply_n(
    const float* __restrict__ x, const float* __restrict__ st,
    const float* __restrict__ gamma, const float* __restrict__ beta, float* __restrict__ out)
{
  int i = blockIdx.x*256 + threadIdx.x;
  if (i >= 524288) return;
  int c = i & 63; int px = i >> 6; int b = px >> 10;
  int g = c >> 1;
  float m = st[(b*32+g)*2], r = st[(b*32+g)*2+1];
  float v = (x[i]-m)*r*gamma[c]+beta[c];
  out[i] = siluf(v);
}

// ---------------- a = silu(gn_noaffine(dseed)*(1+t_scale)+t_shift) (NHWC in/out) ----------------
__global__ __launch_bounds__(256) void k_apply_a_n(
    const float* __restrict__ x, const float* __restrict__ st, const float* __restrict__ tms,
    float* __restrict__ out)
{
  int i = blockIdx.x*256 + threadIdx.x;
  if (i >= 524288) return;
  int c = i & 63; int px = i >> 6; int b = px >> 10;
  int g = c >> 1;
  float m = st[(b*32+g)*2], r = st[(b*32+g)*2+1];
  float v = (x[i]-m)*r;
  v = v*(1.f+tms[b*128+c]) + tms[b*128+64+c];
  out[i] = siluf(v);
}

// ---------------- xmod (NHWC) = xf*(1+scale)+shift ----------------
__global__ __launch_bounds__(256) void k_xmod(
    const float* __restrict__ xf, const float* __restrict__ ph, float* __restrict__ xmod)
{
  int i = blockIdx.x*256 + threadIdx.x;
  if (i >= 8*1024*128) return;
  int c = i & 127; int pix = i >> 7;
  const float* pp = ph + (size_t)pix*384;
  float conf = pp[256 + c];
  float g = 0.3f + 0.7f*sigmoidf_(conf);
  float sc  = pp[c]*g;
  float shf = pp[128 + c]*g;
  xmod[(size_t)pix*128 + c] = xf[(size_t)pix*128 + c]*(1.f+sc)+shf;
}

// ---------------- out-proj epilogue: xx = x + xo*sm_gate (NCHW) ----------------
__global__ __launch_bounds__(256) void k_opj_epi(
    const float* __restrict__ xo, const float* __restrict__ x, const float* __restrict__ cond,
    float* __restrict__ xx)
{
  int i = blockIdx.x*256 + threadIdx.x;
  if (i >= 8*64*1024) return;
  int hw = i & 1023; int c = (i >> 10) & 63; int b = i >> 16;
  int pix = b*1024 + hw;
  float g = cond[((size_t)(b*512+128+c))*1024 + hw];
  xx[i] = x[i] + xo[(size_t)pix*64 + c]*g;
}

// ---------------- fc1 with fused LN2-modulated A-load; gelu epilogue ----------------
__global__ __launch_bounds__(256) void gemm_fc1(
    const float* __restrict__ xx, const float* __restrict__ cond, const float* __restrict__ ln2,
    const float* __restrict__ W, const float* __restrict__ bias, float* __restrict__ C)
{
  __shared__ float As[16][68];
  __shared__ float Ws[16][68];
  const int N = 256, K = 64;
  int bm = blockIdx.y*64, bn = blockIdx.x*64;
  int tid = threadIdx.x;
  int tm = (tid >> 4) << 2;
  int tn = (tid & 15) << 2;
  float acc[4][4] = {};
  for (int k0 = 0; k0 < K; k0 += 16){
    #pragma unroll
    for (int i = 0; i < 4; i++){
      int idx = tid + 256*i;
      int r = idx & 63, cc = idx >> 6;
      int gm = bm + r;
      int b = gm >> 10, hw = gm & 1023;
      int k = k0 + cc;
      float mean = ln2[b*2], rstd = ln2[b*2+1];
      float v  = (xx[((size_t)(b*64+k))*1024 + hw] - mean)*rstd;
      float sc = cond[((size_t)(b*512+256+k))*1024 + hw];
      float sh = cond[((size_t)(b*512+192+k))*1024 + hw];
      As[cc][r] = v*(1.f+sc)+sh;
      int r2 = idx >> 4, cc2 = idx & 15;
      int gn = bn + r2;
      Ws[cc2][r2] = W[(size_t)gn*K + k0 + cc2];
    }
    __syncthreads();
    #pragma unroll
    for (int kk = 0; kk < 16; kk++){
      float a[4], w[4];
      #pragma unroll
      for (int i = 0; i < 4; i++) a[i] = As[kk][tm+i];
      #pragma unroll
      for (int j = 0; j < 4; j++) w[j] = Ws[kk][tn+j];
      #pragma unroll
      for (int i = 0; i < 4; i++)
        #pragma unroll
        for (int j = 0; j < 4; j++) acc[i][j] = fmaf(a[i], w[j], acc[i][j]);
    }
    __syncthreads();
  }
  #pragma unroll
  for (int i = 0; i < 4; i++){
    int gm = bm + tm + i;
    #pragma unroll
    for (int j = 0; j < 4; j++){
      int gn = bn + tn + j;
      C[(size_t)gm*N + gn] = geluf(acc[i][j] + bias[gn]);
    }
  }
}

// ---------------- MLP epilogue: out = xx + mo*sp_gate (NCHW) ----------------
__global__ __launch_bounds__(256) void k_mlp_epi(
    const float* __restrict__ mo, const float* __restrict__ xx, const float* __restrict__ cond,
    float* __restrict__ out)
{
  int i = blockIdx.x*256 + threadIdx.x;
  if (i >= 8*64*1024) return;
  int hw = i & 1023; int c = (i >> 10) & 63; int b = i >> 16;
  int pix = b*1024 + hw;
  float g = cond[((size_t)(b*512+320+c))*1024 + hw];
  out[i] = xx[i] + mo[(size_t)pix*64 + c]*g;
}

// =====================================================================
extern "C" void kernel_launch(void* const* d_in, const int* in_sizes, int n_in,
                              void* d_out, int out_size, void* d_ws, size_t ws_size,
                              hipStream_t stream)
{
  const float* x         = (const float*)d_in[0];
  const float* cond_base = (const float*)d_in[1];
  const float* cond_hf   = (const float*)d_in[2];
  const float* pan_raw   = (const float*)d_in[3];
  const float* gtok      = (const float*)d_in[4];
  const float* ttok      = (const float*)d_in[5];
  const float* w_in      = (const float*)d_in[6];
  const float* b_in      = (const float*)d_in[7];
  const float* w_dw      = (const float*)d_in[8];
  const float* b_dw      = (const float*)d_in[9];
  const float* w_glob    = (const float*)d_in[10];
  const float* b_glob    = (const float*)d_in[11];
  const float* w_ssmt    = (const float*)d_in[12];
  const float* b_ssmt    = (const float*)d_in[13];
  const float* gamma_gate= (const float*)d_in[14];
  const float* gamma_main= (const float*)d_in[15];
  const float* w_out     = (const float*)d_in[16];
  const float* b_out     = (const float*)d_in[17];
  const float* w_fc1     = (const float*)d_in[18];
  const float* b_fc1     = (const float*)d_in[19];
  const float* w_fc2     = (const float*)d_in[20];
  const float* b_fc2     = (const float*)d_in[21];
  const float* m_in_w    = (const float*)d_in[22];
  const float* m_conv_w  = (const float*)d_in[23];
  const float* m_conv_b  = (const float*)d_in[24];
  const float* m_xproj_w = (const float*)d_in[25];
  const float* m_dt_w    = (const float*)d_in[26];
  const float* m_dt_b    = (const float*)d_in[27];
  const float* m_Alog    = (const float*)d_in[28];
  const float* m_D       = (const float*)d_in[29];
  const float* m_out_w   = (const float*)d_in[30];
  const float* pp1_w     = (const float*)d_in[31];
  const float* pp1_b     = (const float*)d_in[32];
  const float* pp_g1     = (const float*)d_in[33];
  const float* pp_b1     = (const float*)d_in[34];
  const float* pp2_w     = (const float*)d_in[35];
  const float* pp2_b     = (const float*)d_in[36];
  const float* al_w      = (const float*)d_in[37];
  const float* al_b      = (const float*)d_in[38];
  const float* alpha_aux = (const float*)d_in[39];
  const float* en_w      = (const float*)d_in[40];
  const float* en_b      = (const float*)d_in[41];
  const float* sf1_w     = (const float*)d_in[42];
  const float* sf_g1     = (const float*)d_in[43];
  const float* sf_b1     = (const float*)d_in[44];
  const float* sf2_w     = (const float*)d_in[45];
  const float* sf_g2     = (const float*)d_in[46];
  const float* sf_b2     = (const float*)d_in[47];
  const float* sf3_w     = (const float*)d_in[48];
  const float* sf3_b     = (const float*)d_in[49];
  const float* tm_w      = (const float*)d_in[50];
  const float* tm_b      = (const float*)d_in[51];
  const float* ph_w      = (const float*)d_in[52];
  const float* ph_b      = (const float*)d_in[53];
  float* out = (float*)d_out;

  float* W = (float*)d_ws;
  size_t off = 0;
  auto alloc = [&](size_t n){ float* p = W + off; off += n; return p; };
  float* glob    = alloc(512);
  float* tt      = alloc(2048);
  float* tms     = alloc(1024);
  float* ln1     = alloc(16);
  float* ln2     = alloc(16);
  float* lnpart  = alloc(2048);      // 512 × double2 partials (8-byte aligned: off is even)
  float* gn1     = alloc(512);
  float* gn2     = alloc(512);
  float* gn3     = alloc(512);
  float* gn4     = alloc(512);
  float* dS      = alloc(8192);
  float* dL      = alloc(8192);
  float* eB      = alloc(8192);
  float* w_inT   = alloc(16384);
  float* wT4     = alloc(147456);    // 4 transposed conv weights [64][576]
  float* sf1Wp   = alloc(8192);      // [64][128]
  float* sf1dot  = alloc(128);       // dot1|dot2
  float* cbn     = alloc(524288);    // cond_feat+glob, NHWC [8192][64]
  float* xgate   = alloc(1048576);   // NHWC [8192][128]; later reused as xmod
  float* xss     = alloc(1048576);   // NHWC [8192][128]; later reused as xo
  float* seq_x   = alloc(4194304);   // later: mamba_out
  float* xm_pre  = alloc(8388608);   // later: y (scanC out)
  float* z_silu  = alloc(8388608);   // later: phb
  float* xm      = alloc(8388608);
  float* xdbl    = alloc(1310720);
  float* scr     = alloc(8388608);   // scans: Pb|Qb; physics: part|cat|hfn; MLP: hid|mo2
  float* xf      = alloc(1048576);   // NHWC [8192][128]
  float* fbuf    = alloc(524288);    // NHWC; later: act_n
  float* actb    = alloc(524288);    // NHWC
  float* sbuf    = alloc(524288);    // NHWC
  float* s2buf   = alloc(524288);    // NHWC
  float* dseed   = alloc(524288);    // NHWC
  float* xxb     = alloc(524288);
  if (ws_size < off*sizeof(float)) return;

  // aliases (stream-order lifetimes verified)
  double* lnps     = (double*)lnpart;
  float* Pb        = scr;               // scans: 1024 blk × 256 × 16 = 4M floats (16MB); scanM overwrites with prefix H
  float* Qb        = scr + 4194304;
  float* yscan     = xm_pre;            // after conv1d
  float* mamba_out = seq_x;             // after scanC (seq dead post in_proj)
  float* phb       = z_silu;            // after scanC (z dead)
  float* xmod      = xgate;             // after k_fuse
  float* xo        = xss;               // after k_dwconv
  float* act_n     = fbuf;              // after gn1 apply consumed
  float* part      = scr;               // physics phase (scans done)
  float* cat       = scr + 1572864;     // [8192][128]: phys | learned
  float* hfn       = scr + 2621440;     // cond_hf NHWC
  float* hid       = scr;               // MLP phase
  float* mo2       = scr + 2097152;

  // ---- main path ----
  k_small3<<<896,256,0,stream>>>(gtok, ttok, w_glob, b_glob, w_ssmt, b_ssmt, tm_w, tm_b, glob, tt, tms);
  k_wT<<<64,256,0,stream>>>(w_in, w_inT);
  k_ln_part<<<512,256,0,stream>>>(x, lnps);
  k_ln_fin<<<8,64,0,stream>>>(lnps, ln1, 1e-6f);
  k_xp<<<512,256,0,stream>>>(x, cond_base, ln1, glob, w_inT, b_in, gamma_gate, xss, xgate, cbn);
  k_dwconv<<<4096,256,0,stream>>>(xss, w_dw, b_dw, cbn, tt, gamma_main, seq_x);
  gemm_in<<<dim3(8,512),256,0,stream>>>(seq_x, m_in_w, xm_pre, z_silu);
  k_conv1d<<<32768,256,0,stream>>>(xm_pre, m_conv_w, m_conv_b, xm);
  gemm_nt<0><<<dim3(1,512),256,0,stream>>>(xm, m_xproj_w, nullptr, xdbl, 32768, 40, 256);
  k_scanA<<<1024,256,0,stream>>>(xm, xdbl, m_dt_w, m_dt_b, m_Alog, Pb, Qb);
  k_scanM<<<dim3(4,32),64,0,stream>>>(Pb, Qb);
  k_scanC<<<1024,256,0,stream>>>(xm, xdbl, m_dt_w, m_dt_b, m_Alog, Pb, m_D, z_silu, yscan);
  gemm_nt<0><<<dim3(2,512),256,0,stream>>>(yscan, m_out_w, nullptr, mamba_out, 32768, 128, 256);
  k_fuse<<<4096,256,0,stream>>>(mamba_out, xgate, xf);

  // ---- physics path (NHWC; scr reused as part/cat/hfn after scans) ----
  k_phys1<<<8,256,0,stream>>>(pan_raw, dS, dL, eB);
  k_wconvT<<<576,256,0,stream>>>(pp2_w, al_w, sf2_w, sf3_w, wT4);
  k_sf1prep<<<1,256,0,stream>>>(sf1_w, en_w, en_b, alpha_aux, sf1Wp, sf1dot);
  k_hfT<<<2048,256,0,stream>>>(cond_hf, hfn);
  k_conv_pp1_n<<<2048,256,0,stream>>>(dS, dL, pp1_w, pp1_b, fbuf);
  k_gn_stats_n<<<256,256,0,stream>>>(fbuf, gn1, 1e-5f);
  k_gn_apply_n<<<2048,256,0,stream>>>(fbuf, gn1, pp_g1, pp_b1, actb);
  k_conv_gemm<<<dim3(3,128),256,0,stream>>>(actb, wT4, part);
  k_conv_red<<<2048,256,0,stream>>>(part, pp2_b, nullptr, 0, cat, 128);          // physf -> cat[:,0:64]
  k_conv_gemm<<<dim3(3,128),256,0,stream>>>(hfn, wT4 + 36864, part);
  k_conv_red<<<2048,256,0,stream>>>(part, al_b, nullptr, 0, cat + 64, 128);      // learned -> cat[:,64:128]
  gemm_sfuse<<<128,256,0,stream>>>(cat, sf1Wp, eB, sf1dot, sbuf);
  k_gn_stats_n<<<256,256,0,stream>>>(sbuf, gn2, 1e-5f);
  k_gn_apply_n<<<2048,256,0,stream>>>(sbuf, gn2, sf_g1, sf_b1, actb);
  k_conv_gemm<<<dim3(3,128),256,0,stream>>>(actb, wT4 + 2*36864, part);
  k_conv_red<<<2048,256,0,stream>>>(part, nullptr, nullptr, 0, s2buf, 64);
  k_gn_stats_n<<<256,256,0,stream>>>(s2buf, gn3, 1e-5f);
  k_gn_apply_n<<<2048,256,0,stream>>>(s2buf, gn3, sf_g2, sf_b2, actb);
  k_conv_gemm<<<dim3(3,128),256,0,stream>>>(actb, wT4 + 3*36864, part);
  k_conv_red<<<2048,256,0,stream>>>(part, sf3_b, cat, 128, dseed, 64);           // + physf resid
  k_gn_stats_n<<<256,256,0,stream>>>(dseed, gn4, 1e-5f);
  k_apply_a_n<<<2048,256,0,stream>>>(dseed, gn4, tms, act_n);
  gemm_nt<0><<<dim3(6,128),256,0,stream>>>(act_n, ph_w, ph_b, phb, 8192, 384, 64);

  // ---- merge + output projection + MLP ----
  k_xmod<<<4096,256,0,stream>>>(xf, phb, xmod);
  gemm_nt<0><<<dim3(1,128),256,0,stream>>>(xmod, w_out, b_out, xo, 8192, 64, 128);
  k_opj_epi<<<2048,256,0,stream>>>(xo, x, cond_base, xxb);
  k_ln_part<<<512,256,0,stream>>>(xxb, lnps);
  k_ln_fin<<<8,64,0,stream>>>(lnps, ln2, 1e-6f);
  gemm_fc1<<<dim3(4,128),256,0,stream>>>(xxb, cond_base, ln2, w_fc1, b_fc1, hid);
  gemm_nt<0><<<dim3(1,128),256,0,stream>>>(hid, w_fc2, b_fc2, mo2, 8192, 64, 256);
  k_mlp_epi<<<2048,256,0,stream>>>(mo2, xxb, cond_base, out);

  (void)in_sizes; (void)n_in; (void)out_size;
}